// Round 1
// baseline (922.969 us; speedup 1.0000x reference)
//
#include <hip/hip_runtime.h>
#include <hip/hip_cooperative_groups.h>
#include <stdint.h>

namespace cg = cooperative_groups;

#define T_CTX 1024
#define DM 64
#define NH 2
#define HD 32
#define DFF 256
#define NVOCAB 8192

typedef int v4i __attribute__((ext_vector_type(4)));

__device__ __forceinline__ int clampi(int v, int lo, int hi){ return v<lo?lo:(v>hi?hi:v); }
__device__ __forceinline__ int wrap8(int v){ return ((v + 128) & 255) - 128; }
__device__ __forceinline__ int sdot4(int a, int b, int c){ return __builtin_amdgcn_sdot4(a, b, c, false); }

__device__ __forceinline__ int wave_reduce_add(int v){
  #pragma unroll
  for (int off = 1; off < 64; off <<= 1) v += __shfl_xor(v, off, 64);
  return v;
}
__device__ __forceinline__ int wave_reduce_max(int v){
  #pragma unroll
  for (int off = 1; off < 64; off <<= 1){ int o = __shfl_xor(v, off, 64); v = o > v ? o : v; }
  return v;
}

// rmsnorm_hw forward: exact integer pipeline; lane == channel (wave64 == DM)
__device__ __forceinline__ int rmsnorm_one(int xv, int g){
  int ss  = wave_reduce_add(xv * xv);
  int ms  = ss >> 6;                 // /64 == /d_model
  int lut = ms >> 6; if (lut > 255) lut = 255;
  int bc  = lut * 64 + 32;           // >= 32, so max(.,1) vacuous
  int inv = (int)__builtin_rint(16384.0 / __builtin_sqrt((double)bc)); // <= 2897 < 16383
  int p1  = (xv * inv) >> 8;         // arithmetic shift == floor
  int y   = (p1 * g) >> 10;
  return clampi(y, -128, 127);
}

// ---------------- per-token stage (device fn): [embed] -> [post] -> [pre] / [final] ----------------
__device__ __forceinline__ void token_phase(
    int blk, const int* __restrict__ tokens, const float* __restrict__ tok_emb,
    const float* __restrict__ pos_emb, int8_t* __restrict__ x, const int8_t* __restrict__ aArr,
    int8_t* __restrict__ qA, int8_t* __restrict__ kA, int8_t* __restrict__ vT,
    const int8_t* __restrict__ wt, const int16_t* __restrict__ gq, int8_t* __restrict__ xf,
    int do_embed, int post_layer, int pre_layer, int do_final,
    int8_t (*sh8)[DFF])
{
  int w = threadIdx.x >> 6, lane = threadIdx.x & 63;
  int t = blk * 4 + w;                    // token 0..4095
  int8_t* myS = sh8[w];
  __syncthreads();                        // LDS reuse guard vs previous phase
  int xv;
  if (do_embed) {
    int tok = tokens[t];
    int s = t & (T_CTX - 1);
    int tq = clampi((int)__builtin_rintf(tok_emb[tok*DM + lane] * 1024.0f), -32768, 32767);
    int pq = clampi((int)__builtin_rintf(pos_emb[s*DM + lane] * 1024.0f), -32768, 32767);
    xv = wrap8((tq + pq) >> 3);
  } else {
    xv = (int)x[t*DM + lane];
  }
  if (post_layer >= 0) {
    const int8_t* wtL = wt + post_layer*49152;
    myS[lane] = aArr[t*DM + lane];
    __syncthreads();
    { // o-projection (bitlinear), out channel = lane
      const int* a4 = (const int*)myS;
      const int* wo = (const int*)(wtL + 12288);
      int acc = 0;
      #pragma unroll
      for (int i = 0; i < 16; i++) acc = sdot4(a4[i], wo[lane*16 + i], acc);
      xv = wrap8(xv + clampi(acc >> 6, -128, 127));
    }
    __syncthreads();
    int h2 = rmsnorm_one(xv, (int)gq[(4 + post_layer)*DM + lane]);
    myS[lane] = (int8_t)h2;
    __syncthreads();
    int uv[4];
    { // up projection: 256 outputs, 4 per lane
      const int* h4 = (const int*)myS;
      const int* wu = (const int*)(wtL + 16384);
      #pragma unroll
      for (int jj = 0; jj < 4; jj++) {
        int j = jj*64 + lane;
        int acc = 0;
        #pragma unroll
        for (int i = 0; i < 16; i++) acc = sdot4(h4[i], wu[j*16 + i], acc);
        int u = clampi(acc >> 6, -128, 127);
        uv[jj] = u < 0 ? 0 : u;           // relu (then int8 clamp is identity)
      }
    }
    __syncthreads();
    #pragma unroll
    for (int jj = 0; jj < 4; jj++) myS[jj*64 + lane] = (int8_t)uv[jj];
    __syncthreads();
    { // down projection: in-dim 256
      const int* u4 = (const int*)myS;
      const int* wd = (const int*)(wtL + 32768);
      int acc = 0;
      #pragma unroll
      for (int i = 0; i < 64; i++) acc = sdot4(u4[i], wd[lane*64 + i], acc);
      xv = wrap8(xv + clampi(acc >> 6, -128, 127));
    }
    __syncthreads();
  }
  x[t*DM + lane] = (int8_t)xv;
  if (pre_layer >= 0) {
    int h = rmsnorm_one(xv, (int)gq[pre_layer*DM + lane]);
    myS[lane] = (int8_t)h;
    __syncthreads();
    const int8_t* wtL = wt + pre_layer*49152;
    const int* h4 = (const int*)myS;
    int b = t >> 10, s = t & (T_CTX - 1);
    int hh = lane >> 5, d = lane & 31;
    int bhh = b*NH + hh;
    { // q
      const int* wm = (const int*)(wtL + 0);
      int acc = 0;
      #pragma unroll
      for (int i = 0; i < 16; i++) acc = sdot4(h4[i], wm[lane*16 + i], acc);
      qA[(bhh*T_CTX + s)*HD + d] = (int8_t)clampi(acc >> 6, -128, 127);
    }
    { // k
      const int* wm = (const int*)(wtL + 4096);
      int acc = 0;
      #pragma unroll
      for (int i = 0; i < 16; i++) acc = sdot4(h4[i], wm[lane*16 + i], acc);
      kA[(bhh*T_CTX + s)*HD + d] = (int8_t)clampi(acc >> 6, -128, 127);
    }
    { // v -> transposed layout
      const int* wm = (const int*)(wtL + 8192);
      int acc = 0;
      #pragma unroll
      for (int i = 0; i < 16; i++) acc = sdot4(h4[i], wm[lane*16 + i], acc);
      vT[(bhh*HD + d)*T_CTX + s] = (int8_t)clampi(acc >> 6, -128, 127);
    }
  }
  if (do_final) {
    int h = rmsnorm_one(xv, (int)gq[8*DM + lane]);
    xf[t*DM + lane] = (int8_t)h;
  }
}

// ---------------- attention phase (device fn): one virtual block = one (bh, 4 q-rows) ----------------
__device__ __forceinline__ void attn_phase(
    int vb, const int8_t* __restrict__ qA, const int8_t* __restrict__ kA,
    const int8_t* __restrict__ vT, int8_t* __restrict__ aOut,
    int* vt32, int (*sp32)[256])
{
  int w = threadIdx.x >> 6, lane = threadIdx.x & 63;
  int bh = vb & 7, qblk = vb >> 3;
  int qi = 1023 - 4*qblk - w;
  int b = bh >> 1, h = bh & 1;
  const int8_t* qBase = qA + bh*(T_CTX*HD);
  const int8_t* kBase = kA + bh*(T_CTX*HD);
  const int8_t* vTbh  = vT + bh*(HD*T_CTX);

  __syncthreads();   // previous user of vt32 done before restaging

  // stage V^T into LDS: wave w handles d = 4r+w; lanes cover a row's 64 int4s
  #pragma unroll
  for (int r = 0; r < 8; r++) {
    int d = r*4 + w;
    int4 v = *(const int4*)(vTbh + d*T_CTX + lane*16);
    int* dst = vt32 + d*257 + lane*4;
    dst[0] = v.x; dst[1] = v.y; dst[2] = v.z; dst[3] = v.w;
  }

  // ---- QK^T row + hw softmax (exact) ----
  const int4* qr = (const int4*)(qBase + qi*HD);
  int4 qa = qr[0], qb = qr[1];
  int sc[16];
  int mloc = -(1 << 30);
  #pragma unroll
  for (int j = 0; j < 16; j++) {
    int k = lane + j*64;
    int s;
    if (k <= qi) {
      const int4* kr = (const int4*)(kBase + k*HD);
      int4 ka = kr[0], kb = kr[1];
      int d = 0;
      d = sdot4(qa.x, ka.x, d); d = sdot4(qa.y, ka.y, d);
      d = sdot4(qa.z, ka.z, d); d = sdot4(qa.w, ka.w, d);
      d = sdot4(qb.x, kb.x, d); d = sdot4(qb.y, kb.y, d);
      d = sdot4(qb.z, kb.z, d); d = sdot4(qb.w, kb.w, d);
      s = (d * 45) >> 8;                  // floor; diag k==q gives s>=0 so the -32767 mask never wins
    } else s = -(1 << 30);
    sc[j] = s; if (s > mloc) mloc = s;
  }
  int m = wave_reduce_max(mloc);
  int ssum = 0;
  #pragma unroll
  for (int j = 0; j < 16; j++) {
    int k = lane + j*64;
    int e = 0;
    if (k <= qi) {
      int sh = sc[j] - m;                 // <= 0
      e = (sh >= -3) ? (256 + sh*64)
        : (sh >= -8) ? (64 + (sh + 3)*11)
        : (sh >= -24) ? (sh + 24) : 0;
    }
    sc[j] = e; ssum += e;
  }
  int s0 = wave_reduce_add(ssum); if (s0 < 1) s0 = 1;
  float sf = (float)s0;
  uint8_t* spb = (uint8_t*)sp32[w];
  #pragma unroll
  for (int j = 0; j < 16; j++) {
    int k = lane + j*64;
    // e==0 for k>qi so the same formula writes the zero padding
    int p = (int)__builtin_rintf((float)sc[j] / sf * 255.0f);
    spb[k] = (uint8_t)clampi(p, 0, 255);
  }
  __syncthreads();   // vt32 + this wave's prob row visible

  // ---- PV via packed sdot4: p = 2*(p>>1) + (p&1) ----
  int dg = lane & 7, kc = lane >> 3;
  const int* vr0 = vt32 + (dg*4 + 0)*257;
  const int* vr1 = vt32 + (dg*4 + 1)*257;
  const int* vr2 = vt32 + (dg*4 + 2)*257;
  const int* vr3 = vt32 + (dg*4 + 3)*257;
  const int* spw = sp32[w];
  int hi0=0, hi1=0, hi2=0, hi3=0, lo0=0, lo1=0, lo2=0, lo3=0;
  int cmax = qi >> 2;
  for (int c = kc; c <= cmax; c += 8) {
    int p4 = spw[c];
    int ph = (p4 >> 1) & 0x7f7f7f7f;
    int pl = p4 & 0x01010101;
    int v0 = vr0[c], v1 = vr1[c], v2 = vr2[c], v3 = vr3[c];
    hi0 = sdot4(ph, v0, hi0); lo0 = sdot4(pl, v0, lo0);
    hi1 = sdot4(ph, v1, hi1); lo1 = sdot4(pl, v1, lo1);
    hi2 = sdot4(ph, v2, hi2); lo2 = sdot4(pl, v2, lo2);
    hi3 = sdot4(ph, v3, hi3); lo3 = sdot4(pl, v3, lo3);
  }
  int a0 = 2*hi0 + lo0, a1 = 2*hi1 + lo1, a2 = 2*hi2 + lo2, a3 = 2*hi3 + lo3;
  #pragma unroll
  for (int off = 8; off < 64; off <<= 1) {
    a0 += __shfl_xor(a0, off, 64);
    a1 += __shfl_xor(a1, off, 64);
    a2 += __shfl_xor(a2, off, 64);
    a3 += __shfl_xor(a3, off, 64);
  }
  if (kc == 0) {
    int r0 = wrap8(a0 >> 8) & 255;
    int r1 = wrap8(a1 >> 8) & 255;
    int r2 = wrap8(a2 >> 8) & 255;
    int r3 = wrap8(a3 >> 8) & 255;
    int packed = r0 | (r1 << 8) | (r2 << 16) | (r3 << 24);
    *(int*)(aOut + (b*T_CTX + qi)*DM + h*HD + dg*4) = packed;
  }
}

// ---------------- fully fused forward: one cooperative kernel, grid syncs replace launches ----------------
__global__ __launch_bounds__(256, 4) void fused(
    const int* __restrict__ tokens, const float* __restrict__ tok_emb, const float* __restrict__ pos_emb,
    const float* __restrict__ anw, const float* __restrict__ qw, const float* __restrict__ kw,
    const float* __restrict__ vw, const float* __restrict__ ow, const float* __restrict__ fnw,
    const float* __restrict__ uw, const float* __restrict__ dw, const float* __restrict__ finw,
    float* __restrict__ out, char* __restrict__ ws)
{
  // shared memory union: attn is the biggest user (36,992 B -> 4 blocks/CU on 160 KiB LDS)
  __shared__ __align__(16) int smem[32*257 + 4*256];
  int* vt32 = smem;
  int (*sp32)[256] = (int(*)[256])(smem + 32*257);
  int8_t (*sh8)[DFF] = (int8_t(*)[DFF])smem;
  double* sred = (double*)smem;

  int8_t*  x   = (int8_t*)(ws + 0);        // 4096*64
  int8_t*  a   = (int8_t*)(ws + 262144);   // 4096*64 attn output (token-major)
  int8_t*  qA  = (int8_t*)(ws + 524288);   // [b][h][t][d]
  int8_t*  kA  = (int8_t*)(ws + 786432);   // [b][h][t][d]
  int8_t*  vT  = (int8_t*)(ws + 1048576);  // [b][h][d][t]  (transposed V)
  int8_t*  wt  = (int8_t*)(ws + 1310720);  // 4 layers * 49152 ternary weights
  int8_t*  elo = (int8_t*)(ws + 1507328);  // 8192*64
  int8_t*  ehi = (int8_t*)(ws + 2031616);  // 8192*64
  int16_t* gq  = (int16_t*)(ws + 2555904); // 9*64
  int8_t*  xf  = (int8_t*)(ws + 2560000);  // 4096*64

  cg::grid_group grid = cg::this_grid();
  int tid = threadIdx.x, bid = blockIdx.x, nb = gridDim.x;

  // ================= phase 0: weight/norm/embedding prep =================
  if (bid < 24) {
    int layer = bid / 6, kind = bid % 6;
    const float* src; int n; int off;
    switch (kind) {
      case 0:  src = qw + layer*4096;  n = 4096;  off = 0;     break;
      case 1:  src = kw + layer*4096;  n = 4096;  off = 4096;  break;
      case 2:  src = vw + layer*4096;  n = 4096;  off = 8192;  break;
      case 3:  src = ow + layer*4096;  n = 4096;  off = 12288; break;
      case 4:  src = uw + layer*16384; n = 16384; off = 16384; break;
      default: src = dw + layer*16384; n = 16384; off = 32768; break;
    }
    double s = 0.0;
    for (int i = tid; i < n; i += 256) s += (double)__builtin_fabsf(src[i]);
    sred[tid] = s; __syncthreads();
    for (int st = 128; st > 0; st >>= 1){ if (tid < st) sred[tid] += sred[tid + st]; __syncthreads(); }
    float fs = (float)(sred[0] / (double)n);
    if (fs < 1e-5f) fs = 1e-5f;
    int8_t* dst = wt + layer*49152 + off;
    for (int i = tid; i < n; i += 256) {
      int t = (int)__builtin_rintf(src[i] / fs);
      dst[i] = (int8_t)clampi(t, -1, 1);
    }
  } else if (bid == 24) {
    // 9 norms x 64 channels: 0..3 attn, 4..7 ffn, 8 final
    for (int i = tid; i < 576; i += 256) {
      int norm = i >> 6, c = i & 63;
      const float* wsrc = (norm < 4) ? (anw + norm*64) : (norm < 8) ? (fnw + (norm-4)*64) : finw;
      float wv = wsrc[c];
      float wc = wv < -2.0f ? -2.0f : (wv > 2.0f ? 2.0f : wv);
      gq[i] = (int16_t)clampi((int)__builtin_rintf(wc * 1024.0f), -32768, 32767);
    }
  } else {
    // embedding hi/lo split, grid-strided over remaining blocks
    int base = (bid - 25)*256 + tid;
    int stride = (nb - 25)*256;
    for (int i = base; i < NVOCAB*DM; i += stride) {
      int e  = clampi((int)__builtin_rintf(tok_emb[i] * 1024.0f), -32768, 32767);
      int l  = ((e + 128) & 255) - 128;   // signed low byte
      int hh = (e - l) >> 8;              // e == 256*hh + l
      if (hh > 127) hh = 127;             // unreachable for |emb| < 31.9 sigma
      elo[i] = (int8_t)l; ehi[i] = (int8_t)hh;
    }
  }
  grid.sync();

  // ================= embed + pre-layer-0 =================
  for (int vb = bid; vb < 1024; vb += nb)
    token_phase(vb, tokens, tok_emb, pos_emb, x, a, qA, kA, vT, wt, gq, xf, 1, -1, 0, 0, sh8);
  grid.sync();

  // ================= 4 transformer layers =================
  for (int L = 0; L < 4; L++) {
    // attention: 2048 virtual blocks; pair vb / 2047-vb so heavy+light causal rows balance
    for (int vb = bid; vb < 1024; vb += nb) {
      attn_phase(vb,        qA, kA, vT, a, vt32, sp32);
      attn_phase(2047 - vb, qA, kA, vT, a, vt32, sp32);
    }
    grid.sync();
    int pre = (L < 3) ? (L + 1) : -1;
    int fin = (L == 3) ? 1 : 0;
    for (int vb = bid; vb < 1024; vb += nb)
      token_phase(vb, tokens, tok_emb, pos_emb, x, a, qA, kA, vT, wt, gq, xf, 0, L, pre, fin, sh8);
    grid.sync();
  }

  // ================= logits: xf[4096x64] x emb(hi/lo)[8192x64]^T via i8 MFMA =================
  for (int vb = bid; vb < 4096; vb += nb) {
    int by = vb >> 6, bx = vb & 63;
    int w = tid >> 6, lane = tid & 63;
    int m = lane & 15, quad = lane >> 4;
    int tokBase = by * 64 + w * 16;
    v4i A = *(const v4i*)(xf + (tokBase + m)*DM + quad*16);  // A[m=lane&15][k=quad*16+j]
    #pragma unroll
    for (int tile = 0; tile < 8; tile++) {
      int vocBase = bx * 128 + tile * 16;
      v4i Blo = *(const v4i*)(elo + (vocBase + m)*DM + quad*16);
      v4i Bhi = *(const v4i*)(ehi + (vocBase + m)*DM + quad*16);
      v4i zero = {0, 0, 0, 0};
      v4i dLo = __builtin_amdgcn_mfma_i32_16x16x64_i8(A, Blo, zero, 0, 0, 0);
      v4i dHi = __builtin_amdgcn_mfma_i32_16x16x64_i8(A, Bhi, zero, 0, 0, 0);
      #pragma unroll
      for (int r = 0; r < 4; r++) {
        int val = dLo[r] + (dHi[r] << 8);                     // dot(x, 256*hi + lo), exact int32
        int row = tokBase + quad*4 + r;                       // C/D: row=(lane>>4)*4+reg
        int col = vocBase + m;                                // col=lane&15
        out[row*NVOCAB + col] = (float)val * 1.220703125e-4f; // * 2^-13 == D^-0.5/1024
      }
    }
  }
}

extern "C" void kernel_launch(void* const* d_in, const int* in_sizes, int n_in,
                              void* d_out, int out_size, void* d_ws, size_t ws_size,
                              hipStream_t stream)
{
  const int*   tokens  = (const int*)d_in[0];
  const float* tok_emb = (const float*)d_in[1];
  const float* pos_emb = (const float*)d_in[2];
  const float* attn_nw = (const float*)d_in[3];
  const float* q_w     = (const float*)d_in[4];
  const float* k_w     = (const float*)d_in[5];
  const float* v_w     = (const float*)d_in[6];
  const float* o_w     = (const float*)d_in[7];
  const float* ff_nw   = (const float*)d_in[8];
  const float* up_w    = (const float*)d_in[9];
  const float* dn_w    = (const float*)d_in[10];
  const float* fin_nw  = (const float*)d_in[11];
  float* out = (float*)d_out;
  char* ws = (char*)d_ws;

  // co-resident grid size, cached (host-only queries; capture-safe)
  static int nblk = 0;
  if (nblk == 0) {
    int perCU = 0;
    if (hipOccupancyMaxActiveBlocksPerMultiprocessor(&perCU, (const void*)fused, 256, 0) != hipSuccess
        || perCU < 1) perCU = 4;
    int dev = 0; hipGetDevice(&dev);
    hipDeviceProp_t prop{};
    int ncu = 256;
    if (hipGetDeviceProperties(&prop, dev) == hipSuccess && prop.multiProcessorCount > 0)
      ncu = prop.multiProcessorCount;
    long tot = (long)perCU * (long)ncu;
    nblk = (int)(tot < 1024 ? tot : 1024);
    if (nblk < 26) nblk = 26;   // prep-phase role assignment needs >=26 blocks
  }

  void* args[] = { &tokens, &tok_emb, &pos_emb, &attn_nw, &q_w, &k_w, &v_w, &o_w,
                   &ff_nw, &up_w, &dn_w, &fin_nw, &out, &ws };
  hipLaunchCooperativeKernel((const void*)fused, dim3(nblk), dim3(256), args, 0, stream);
}

// Round 2
// 429.678 us; speedup vs baseline: 2.1481x; 2.1481x over previous
//
#include <hip/hip_runtime.h>
#include <stdint.h>

#define T_CTX 1024
#define DM 64
#define NH 2
#define HD 32
#define DFF 256
#define NVOCAB 8192

typedef int v4i __attribute__((ext_vector_type(4)));

__device__ __forceinline__ int clampi(int v, int lo, int hi){ return v<lo?lo:(v>hi?hi:v); }
__device__ __forceinline__ int wrap8(int v){ return ((v + 128) & 255) - 128; }
__device__ __forceinline__ int sdot4(int a, int b, int c){ return __builtin_amdgcn_sdot4(a, b, c, false); }

__device__ __forceinline__ int wave_reduce_add(int v){
  #pragma unroll
  for (int off = 1; off < 64; off <<= 1) v += __shfl_xor(v, off, 64);
  return v;
}
__device__ __forceinline__ int wave_reduce_max(int v){
  #pragma unroll
  for (int off = 1; off < 64; off <<= 1){ int o = __shfl_xor(v, off, 64); v = o > v ? o : v; }
  return v;
}

// rmsnorm_hw forward: exact integer pipeline; lane == channel (wave64 == DM)
__device__ __forceinline__ int rmsnorm_one(int xv, int g){
  int ss  = wave_reduce_add(xv * xv);
  int ms  = ss >> 6;                 // /64 == /d_model
  int lut = ms >> 6; if (lut > 255) lut = 255;
  int bc  = lut * 64 + 32;           // >= 32, so max(.,1) vacuous
  int inv = (int)__builtin_rint(16384.0 / __builtin_sqrt((double)bc)); // <= 2897 < 16383
  int p1  = (xv * inv) >> 8;         // arithmetic shift == floor
  int y   = (p1 * g) >> 10;
  return clampi(y, -128, 127);
}

// ---------------- prep (single kernel): ternarize weights + quantize gammas + split embedding ----------------
__global__ __launch_bounds__(256) void prep_all(
    const float* __restrict__ qw, const float* __restrict__ kw, const float* __restrict__ vw,
    const float* __restrict__ ow, const float* __restrict__ uw, const float* __restrict__ dw,
    const float* __restrict__ anw, const float* __restrict__ fnw, const float* __restrict__ finw,
    const float* __restrict__ tok_emb,
    int8_t* __restrict__ wt, int16_t* __restrict__ gq,
    int8_t* __restrict__ elo, int8_t* __restrict__ ehi)
{
  int tid = threadIdx.x;
  int bid = blockIdx.x;
  if (bid < 24) {
    int layer = bid / 6, kind = bid % 6;
    const float* src; int n; int off;
    switch (kind) {
      case 0:  src = qw + layer*4096;  n = 4096;  off = 0;     break;
      case 1:  src = kw + layer*4096;  n = 4096;  off = 4096;  break;
      case 2:  src = vw + layer*4096;  n = 4096;  off = 8192;  break;
      case 3:  src = ow + layer*4096;  n = 4096;  off = 12288; break;
      case 4:  src = uw + layer*16384; n = 16384; off = 16384; break;
      default: src = dw + layer*16384; n = 16384; off = 32768; break;
    }
    __shared__ double sred[256];
    double s = 0.0;
    for (int i = tid; i < n; i += 256) s += (double)__builtin_fabsf(src[i]);
    sred[tid] = s; __syncthreads();
    for (int st = 128; st > 0; st >>= 1){ if (tid < st) sred[tid] += sred[tid + st]; __syncthreads(); }
    float fs = (float)(sred[0] / (double)n);
    if (fs < 1e-5f) fs = 1e-5f;
    int8_t* dst = wt + layer*49152 + off;
    for (int i = tid; i < n; i += 256) {
      int t = (int)__builtin_rintf(src[i] / fs);
      dst[i] = (int8_t)clampi(t, -1, 1);
    }
  } else if (bid == 24) {
    // 9 norms x 64 channels: 0..3 attn, 4..7 ffn, 8 final
    for (int i = tid; i < 576; i += 256) {
      int norm = i >> 6, c = i & 63;
      const float* wsrc = (norm < 4) ? (anw + norm*64) : (norm < 8) ? (fnw + (norm-4)*64) : finw;
      float wv = wsrc[c];
      float wc = wv < -2.0f ? -2.0f : (wv > 2.0f ? 2.0f : wv);
      gq[i] = (int16_t)clampi((int)__builtin_rintf(wc * 1024.0f), -32768, 32767);
    }
  } else {
    // embedding hi/lo split: blocks 25..2072 cover NVOCAB*DM = 524288 exactly
    int i = (bid - 25)*256 + tid;
    if (i < NVOCAB * DM) {
      int e  = clampi((int)__builtin_rintf(tok_emb[i] * 1024.0f), -32768, 32767);
      int l  = ((e + 128) & 255) - 128;   // signed low byte
      int hh = (e - l) >> 8;              // e == 256*hh + l
      if (hh > 127) hh = 127;             // unreachable for |emb| < 31.9 sigma
      elo[i] = (int8_t)l; ehi[i] = (int8_t)hh;
    }
  }
}

// ---------------- embed + pre-layer-0 QKV: 4 waves/block, one token per wave ----------------
__global__ __launch_bounds__(256) void embed_pre0(
    const int* __restrict__ tokens, const float* __restrict__ tok_emb, const float* __restrict__ pos_emb,
    int8_t* __restrict__ x, int8_t* __restrict__ qA, int8_t* __restrict__ kA, int8_t* __restrict__ vT,
    const int8_t* __restrict__ wt, const int16_t* __restrict__ gq)
{
  __shared__ int8_t sh8[4][64];
  int w = threadIdx.x >> 6, lane = threadIdx.x & 63;
  int t = blockIdx.x * 4 + w;             // token 0..4095
  int tok = tokens[t];
  int s = t & (T_CTX - 1);
  int tq = clampi((int)__builtin_rintf(tok_emb[tok*DM + lane] * 1024.0f), -32768, 32767);
  int pq = clampi((int)__builtin_rintf(pos_emb[s*DM + lane] * 1024.0f), -32768, 32767);
  int xv = wrap8((tq + pq) >> 3);
  x[t*DM + lane] = (int8_t)xv;
  int h = rmsnorm_one(xv, (int)gq[lane]);         // layer-0 attn norm
  sh8[w][lane] = (int8_t)h;
  __syncthreads();
  const int* h4 = (const int*)sh8[w];
  int b = t >> 10;
  int hh = lane >> 5, d = lane & 31;
  int bhh = b*NH + hh;
  const int8_t* wtL = wt;                          // layer 0
  { // q
    const int* wm = (const int*)(wtL + 0);
    int acc = 0;
    #pragma unroll
    for (int i = 0; i < 16; i++) acc = sdot4(h4[i], wm[lane*16 + i], acc);
    qA[(bhh*T_CTX + s)*HD + d] = (int8_t)clampi(acc >> 6, -128, 127);
  }
  { // k
    const int* wm = (const int*)(wtL + 4096);
    int acc = 0;
    #pragma unroll
    for (int i = 0; i < 16; i++) acc = sdot4(h4[i], wm[lane*16 + i], acc);
    kA[(bhh*T_CTX + s)*HD + d] = (int8_t)clampi(acc >> 6, -128, 127);
  }
  { // v -> transposed layout
    const int* wm = (const int*)(wtL + 8192);
    int acc = 0;
    #pragma unroll
    for (int i = 0; i < 16; i++) acc = sdot4(h4[i], wm[lane*16 + i], acc);
    vT[(bhh*HD + d)*T_CTX + s] = (int8_t)clampi(acc >> 6, -128, 127);
  }
}

// ---------------- fused layer: attn (2 tokens x 2 heads, wave=row) + o-proj + FFN + next-layer QKV ----------------
// Block = (batch b, token pair s0,s0+1). Waves: w>>1 = local token, w&1 = head.
// V^T read directly from global (L2-resident, 512 KB/layer) -- no LDS staging.
// qA/kA/vT are double-buffered across layers: reads cur, writes nxt.
__global__ __launch_bounds__(256) void layer_kernel(
    const int8_t* __restrict__ qA, const int8_t* __restrict__ kA, const int8_t* __restrict__ vT,
    int8_t* __restrict__ x, int8_t* __restrict__ qN, int8_t* __restrict__ kN, int8_t* __restrict__ vN,
    const int8_t* __restrict__ wt, const int16_t* __restrict__ gq, int8_t* __restrict__ xf,
    int L, int pre_layer, int do_final)
{
  __shared__ int sp32[4][256];      // probs, one 1024-byte row per wave
  __shared__ int sh_a32[2][16];     // attn output, 64 B per local token
  __shared__ int8_t sh8[2][256];    // FFN temporaries, one row per local token

  int w = threadIdx.x >> 6, lane = threadIdx.x & 63;
  int blk = blockIdx.x;
  int b = blk & 3;
  int s0 = 1022 - 2*(blk >> 2);     // heavy rows first; covers s = 0..1023 over 2048 blocks
  int tl = w >> 1;                  // local token 0..1
  int qi = s0 + tl;
  int h = w & 1;
  int bh = b*NH + h;
  const int8_t* qBase = qA + bh*(T_CTX*HD);
  const int8_t* kBase = kA + bh*(T_CTX*HD);
  const int8_t* vTbh  = vT + bh*(HD*T_CTX);

  // ---- QK^T row + hw softmax (exact) ----
  const int4* qr = (const int4*)(qBase + qi*HD);
  int4 qa = qr[0], qb = qr[1];
  int sc[16];
  int mloc = -(1 << 30);
  #pragma unroll
  for (int j = 0; j < 16; j++) {
    int k = lane + j*64;
    int s;
    if (k <= qi) {
      const int4* kr = (const int4*)(kBase + k*HD);
      int4 ka = kr[0], kb = kr[1];
      int d = 0;
      d = sdot4(qa.x, ka.x, d); d = sdot4(qa.y, ka.y, d);
      d = sdot4(qa.z, ka.z, d); d = sdot4(qa.w, ka.w, d);
      d = sdot4(qb.x, kb.x, d); d = sdot4(qb.y, kb.y, d);
      d = sdot4(qb.z, kb.z, d); d = sdot4(qb.w, kb.w, d);
      s = (d * 45) >> 8;                  // floor; diag k==q gives s>=0 so the -32767 mask never wins
    } else s = -(1 << 30);
    sc[j] = s; if (s > mloc) mloc = s;
  }
  int m = wave_reduce_max(mloc);
  int ssum = 0;
  #pragma unroll
  for (int j = 0; j < 16; j++) {
    int k = lane + j*64;
    int e = 0;
    if (k <= qi) {
      int sh = sc[j] - m;                 // <= 0
      e = (sh >= -3) ? (256 + sh*64)
        : (sh >= -8) ? (64 + (sh + 3)*11)
        : (sh >= -24) ? (sh + 24) : 0;
    }
    sc[j] = e; ssum += e;
  }
  int s0sum = wave_reduce_add(ssum); if (s0sum < 1) s0sum = 1;
  float sf = (float)s0sum;
  uint8_t* spb = (uint8_t*)sp32[w];
  #pragma unroll
  for (int j = 0; j < 16; j++) {
    int k = lane + j*64;
    // e==0 for k>qi so the same formula writes the zero padding
    int p = (int)__builtin_rintf((float)sc[j] / sf * 255.0f);
    spb[k] = (uint8_t)clampi(p, 0, 255);
  }
  __syncthreads();   // prob rows committed (uniform barrier)

  // ---- PV via packed sdot4 straight from global V^T: p = 2*(p>>1) + (p&1) ----
  int dg = lane & 7, kc = lane >> 3;
  const int* vr0 = (const int*)(vTbh + (dg*4 + 0)*T_CTX);
  const int* vr1 = (const int*)(vTbh + (dg*4 + 1)*T_CTX);
  const int* vr2 = (const int*)(vTbh + (dg*4 + 2)*T_CTX);
  const int* vr3 = (const int*)(vTbh + (dg*4 + 3)*T_CTX);
  const int* spw = sp32[w];
  int hi0=0, hi1=0, hi2=0, hi3=0, lo0=0, lo1=0, lo2=0, lo3=0;
  int cmax = qi >> 2;
  for (int c = kc; c <= cmax; c += 8) {
    int p4 = spw[c];
    int ph = (p4 >> 1) & 0x7f7f7f7f;
    int pl = p4 & 0x01010101;
    int v0 = vr0[c], v1 = vr1[c], v2 = vr2[c], v3 = vr3[c];
    hi0 = sdot4(ph, v0, hi0); lo0 = sdot4(pl, v0, lo0);
    hi1 = sdot4(ph, v1, hi1); lo1 = sdot4(pl, v1, lo1);
    hi2 = sdot4(ph, v2, hi2); lo2 = sdot4(pl, v2, lo2);
    hi3 = sdot4(ph, v3, hi3); lo3 = sdot4(pl, v3, lo3);
  }
  int a0 = 2*hi0 + lo0, a1 = 2*hi1 + lo1, a2 = 2*hi2 + lo2, a3 = 2*hi3 + lo3;
  #pragma unroll
  for (int off = 8; off < 64; off <<= 1) {
    a0 += __shfl_xor(a0, off, 64);
    a1 += __shfl_xor(a1, off, 64);
    a2 += __shfl_xor(a2, off, 64);
    a3 += __shfl_xor(a3, off, 64);
  }
  if (kc == 0) {
    int r0 = wrap8(a0 >> 8) & 255;
    int r1 = wrap8(a1 >> 8) & 255;
    int r2 = wrap8(a2 >> 8) & 255;
    int r3 = wrap8(a3 >> 8) & 255;
    int packed = r0 | (r1 << 8) | (r2 << 16) | (r3 << 24);
    sh_a32[tl][h*8 + dg] = packed;     // channel word (h*HD + dg*4)/4
  }
  __syncthreads();   // attn output for both heads visible to token waves

  // ---- token phase: waves 0..1 each own one token; barriers uniform across all 4 waves ----
  int t = b*T_CTX + s0 + w;            // meaningful for w<2
  int xv = 0;
  const int8_t* wtL = wt + L*49152;
  if (w < 2) {
    xv = (int)x[t*DM + lane];
    { // o-projection, out channel = lane
      const int* a4 = sh_a32[w];
      const int* wo = (const int*)(wtL + 12288);
      int acc = 0;
      #pragma unroll
      for (int i = 0; i < 16; i++) acc = sdot4(a4[i], wo[lane*16 + i], acc);
      xv = wrap8(xv + clampi(acc >> 6, -128, 127));
    }
    int h2 = rmsnorm_one(xv, (int)gq[(4 + L)*DM + lane]);
    sh8[w][lane] = (int8_t)h2;
  }
  __syncthreads();
  if (w < 2) {
    int8_t* myS = sh8[w];
    const int* h4 = (const int*)myS;
    int uv[4];
    { // up projection: 256 outputs, 4 per lane
      const int* wu = (const int*)(wtL + 16384);
      #pragma unroll
      for (int jj = 0; jj < 4; jj++) {
        int j = jj*64 + lane;
        int acc = 0;
        #pragma unroll
        for (int i = 0; i < 16; i++) acc = sdot4(h4[i], wu[j*16 + i], acc);
        int u = clampi(acc >> 6, -128, 127);
        uv[jj] = u < 0 ? 0 : u;           // relu (then int8 clamp is identity)
      }
    }
    #pragma unroll
    for (int jj = 0; jj < 4; jj++) myS[jj*64 + lane] = (int8_t)uv[jj];
  }
  __syncthreads();
  if (w < 2) {
    const int* u4 = (const int*)sh8[w];
    { // down projection: in-dim 256
      const int* wd = (const int*)(wtL + 32768);
      int acc = 0;
      #pragma unroll
      for (int i = 0; i < 64; i++) acc = sdot4(u4[i], wd[lane*64 + i], acc);
      xv = wrap8(xv + clampi(acc >> 6, -128, 127));
    }
    x[t*DM + lane] = (int8_t)xv;
  }
  if (pre_layer >= 0) {
    if (w < 2) {
      int hp = rmsnorm_one(xv, (int)gq[pre_layer*DM + lane]);
      sh8[w][lane] = (int8_t)hp;
    }
    __syncthreads();
    if (w < 2) {
      const int* h4 = (const int*)sh8[w];
      const int8_t* wtP = wt + pre_layer*49152;
      int s = s0 + w;
      int hh = lane >> 5, d = lane & 31;
      int bhh = b*NH + hh;
      { // q
        const int* wm = (const int*)(wtP + 0);
        int acc = 0;
        #pragma unroll
        for (int i = 0; i < 16; i++) acc = sdot4(h4[i], wm[lane*16 + i], acc);
        qN[(bhh*T_CTX + s)*HD + d] = (int8_t)clampi(acc >> 6, -128, 127);
      }
      { // k
        const int* wm = (const int*)(wtP + 4096);
        int acc = 0;
        #pragma unroll
        for (int i = 0; i < 16; i++) acc = sdot4(h4[i], wm[lane*16 + i], acc);
        kN[(bhh*T_CTX + s)*HD + d] = (int8_t)clampi(acc >> 6, -128, 127);
      }
      { // v -> transposed layout
        const int* wm = (const int*)(wtP + 8192);
        int acc = 0;
        #pragma unroll
        for (int i = 0; i < 16; i++) acc = sdot4(h4[i], wm[lane*16 + i], acc);
        vN[(bhh*HD + d)*T_CTX + s] = (int8_t)clampi(acc >> 6, -128, 127);
      }
    }
  }
  if (do_final && w < 2) {
    int hf = rmsnorm_one(xv, (int)gq[8*DM + lane]);
    xf[t*DM + lane] = (int8_t)hf;
  }
}

// ---------------- logits: xf[4096x64] int8 x emb(hi/lo int8)[8192x64]^T via i8 MFMA ----------------
__global__ __launch_bounds__(256) void logits_kernel(
    const int8_t* __restrict__ xf, const int8_t* __restrict__ elo, const int8_t* __restrict__ ehi,
    float* __restrict__ out)
{
  int w = threadIdx.x >> 6, lane = threadIdx.x & 63;
  int m = lane & 15, quad = lane >> 4;
  int tokBase = blockIdx.y * 64 + w * 16;
  v4i A = *(const v4i*)(xf + (tokBase + m)*DM + quad*16);  // A[m=lane&15][k=quad*16+j]
  #pragma unroll
  for (int tile = 0; tile < 8; tile++) {
    int vocBase = blockIdx.x * 128 + tile * 16;
    v4i Blo = *(const v4i*)(elo + (vocBase + m)*DM + quad*16);
    v4i Bhi = *(const v4i*)(ehi + (vocBase + m)*DM + quad*16);
    v4i zero = {0, 0, 0, 0};
    v4i dLo = __builtin_amdgcn_mfma_i32_16x16x64_i8(A, Blo, zero, 0, 0, 0);
    v4i dHi = __builtin_amdgcn_mfma_i32_16x16x64_i8(A, Bhi, zero, 0, 0, 0);
    #pragma unroll
    for (int r = 0; r < 4; r++) {
      int val = dLo[r] + (dHi[r] << 8);                     // dot(x, 256*hi + lo), exact int32
      int row = tokBase + quad*4 + r;                       // C/D: row=(lane>>4)*4+reg
      int col = vocBase + m;                                // col=lane&15
      out[row*NVOCAB + col] = (float)val * 1.220703125e-4f; // * 2^-13 == D^-0.5/1024
    }
  }
}

extern "C" void kernel_launch(void* const* d_in, const int* in_sizes, int n_in,
                              void* d_out, int out_size, void* d_ws, size_t ws_size,
                              hipStream_t stream)
{
  const int*   tokens  = (const int*)d_in[0];
  const float* tok_emb = (const float*)d_in[1];
  const float* pos_emb = (const float*)d_in[2];
  const float* attn_nw = (const float*)d_in[3];
  const float* q_w     = (const float*)d_in[4];
  const float* k_w     = (const float*)d_in[5];
  const float* v_w     = (const float*)d_in[6];
  const float* o_w     = (const float*)d_in[7];
  const float* ff_nw   = (const float*)d_in[8];
  const float* up_w    = (const float*)d_in[9];
  const float* dn_w    = (const float*)d_in[10];
  const float* fin_nw  = (const float*)d_in[11];
  float* out = (float*)d_out;
  char* ws = (char*)d_ws;

  int8_t*  x    = (int8_t*)(ws + 0);        // 4096*64 residual stream
  int8_t*  qA0  = (int8_t*)(ws + 262144);   // [b][h][t][d] buffer 0
  int8_t*  kA0  = (int8_t*)(ws + 524288);
  int8_t*  vT0  = (int8_t*)(ws + 786432);   // [b][h][d][t]
  int8_t*  qA1  = (int8_t*)(ws + 1048576);  // buffer 1
  int8_t*  kA1  = (int8_t*)(ws + 1310720);
  int8_t*  vT1  = (int8_t*)(ws + 1572864);
  int8_t*  wt   = (int8_t*)(ws + 1835008);  // 4 layers * 49152 ternary weights
  int8_t*  elo  = (int8_t*)(ws + 2031616);  // 8192*64
  int8_t*  ehi  = (int8_t*)(ws + 2555904);  // 8192*64
  int16_t* gq   = (int16_t*)(ws + 3080192); // 9*64
  int8_t*  xf   = (int8_t*)(ws + 3081344);  // 4096*64

  prep_all<<<2073, 256, 0, stream>>>(q_w, k_w, v_w, o_w, up_w, dn_w, attn_nw, ff_nw, fin_nw,
                                     tok_emb, wt, gq, elo, ehi);
  embed_pre0<<<1024, 256, 0, stream>>>(tokens, tok_emb, pos_emb, x, qA0, kA0, vT0, wt, gq);
  for (int L = 0; L < 4; L++) {
    int8_t* qC = (L & 1) ? qA1 : qA0;  int8_t* qX = (L & 1) ? qA0 : qA1;
    int8_t* kC = (L & 1) ? kA1 : kA0;  int8_t* kX = (L & 1) ? kA0 : kA1;
    int8_t* vC = (L & 1) ? vT1 : vT0;  int8_t* vX = (L & 1) ? vT0 : vT1;
    int pre = (L < 3) ? (L + 1) : -1;
    int fin = (L == 3) ? 1 : 0;
    layer_kernel<<<2048, 256, 0, stream>>>(qC, kC, vC, x, qX, kX, vX, wt, gq, xf, L, pre, fin);
  }
  logits_kernel<<<dim3(64, 64), 256, 0, stream>>>(xf, elo, ehi, out);
}

// Round 3
// 357.792 us; speedup vs baseline: 2.5796x; 1.2009x over previous
//
#include <hip/hip_runtime.h>
#include <stdint.h>

#define T_CTX 1024
#define DM 64
#define NH 2
#define HD 32
#define DFF 256
#define NVOCAB 8192

typedef int v4i __attribute__((ext_vector_type(4)));

__device__ __forceinline__ int clampi(int v, int lo, int hi){ return v<lo?lo:(v>hi?hi:v); }
__device__ __forceinline__ int wrap8(int v){ return ((v + 128) & 255) - 128; }
__device__ __forceinline__ int sdot4(int a, int b, int c){ return __builtin_amdgcn_sdot4(a, b, c, false); }

__device__ __forceinline__ int wave_reduce_add(int v){
  #pragma unroll
  for (int off = 1; off < 64; off <<= 1) v += __shfl_xor(v, off, 64);
  return v;
}
__device__ __forceinline__ int wave_reduce_max(int v){
  #pragma unroll
  for (int off = 1; off < 64; off <<= 1){ int o = __shfl_xor(v, off, 64); v = o > v ? o : v; }
  return v;
}

// rmsnorm_hw forward: exact integer pipeline; lane == channel (wave64 == DM)
__device__ __forceinline__ int rmsnorm_one(int xv, int g){
  int ss  = wave_reduce_add(xv * xv);
  int ms  = ss >> 6;                 // /64 == /d_model
  int lut = ms >> 6; if (lut > 255) lut = 255;
  int bc  = lut * 64 + 32;           // >= 32, so max(.,1) vacuous
  int inv = (int)__builtin_rint(16384.0 / __builtin_sqrt((double)bc)); // <= 2897 < 16383
  int p1  = (xv * inv) >> 8;         // arithmetic shift == floor
  int y   = (p1 * g) >> 10;
  return clampi(y, -128, 127);
}

// ---------------- prep + embed fused (block-range split; halves are independent) ----------------
// bid 0..23   : ternarize weights -> wt
// bid 24      : quantize 9 norm gammas -> gq
// bid 25..2072: split Q5.10 embedding into hi/lo planes
// bid 2073+   : embed tokens + layer-0 QKV (recomputes layer-0 scales bit-identically, no dep on prep)
__global__ __launch_bounds__(256) void prep_embed(
    const int* __restrict__ tokens, const float* __restrict__ tok_emb, const float* __restrict__ pos_emb,
    const float* __restrict__ qw, const float* __restrict__ kw, const float* __restrict__ vw,
    const float* __restrict__ ow, const float* __restrict__ uw, const float* __restrict__ dw,
    const float* __restrict__ anw, const float* __restrict__ fnw, const float* __restrict__ finw,
    int8_t* __restrict__ wt, int16_t* __restrict__ gq,
    int8_t* __restrict__ elo, int8_t* __restrict__ ehi,
    int8_t* __restrict__ x, int8_t* __restrict__ qA, int8_t* __restrict__ kA, int8_t* __restrict__ vT)
{
  __shared__ double sred[256];
  __shared__ int8_t sh_h[4][64];
  int tid = threadIdx.x, bid = blockIdx.x;
  if (bid < 24) {
    int layer = bid / 6, kind = bid % 6;
    const float* src; int n; int off;
    switch (kind) {
      case 0:  src = qw + layer*4096;  n = 4096;  off = 0;     break;
      case 1:  src = kw + layer*4096;  n = 4096;  off = 4096;  break;
      case 2:  src = vw + layer*4096;  n = 4096;  off = 8192;  break;
      case 3:  src = ow + layer*4096;  n = 4096;  off = 12288; break;
      case 4:  src = uw + layer*16384; n = 16384; off = 16384; break;
      default: src = dw + layer*16384; n = 16384; off = 32768; break;
    }
    double s = 0.0;
    for (int i = tid; i < n; i += 256) s += (double)__builtin_fabsf(src[i]);
    sred[tid] = s; __syncthreads();
    for (int st = 128; st > 0; st >>= 1){ if (tid < st) sred[tid] += sred[tid + st]; __syncthreads(); }
    float fs = (float)(sred[0] / (double)n);
    if (fs < 1e-5f) fs = 1e-5f;
    int8_t* dst = wt + layer*49152 + off;
    for (int i = tid; i < n; i += 256) {
      int t = (int)__builtin_rintf(src[i] / fs);
      dst[i] = (int8_t)clampi(t, -1, 1);
    }
  } else if (bid == 24) {
    // 9 norms x 64 channels: 0..3 attn, 4..7 ffn, 8 final
    for (int i = tid; i < 576; i += 256) {
      int norm = i >> 6, c = i & 63;
      const float* wsrc = (norm < 4) ? (anw + norm*64) : (norm < 8) ? (fnw + (norm-4)*64) : finw;
      float wv = wsrc[c];
      float wc = wv < -2.0f ? -2.0f : (wv > 2.0f ? 2.0f : wv);
      gq[i] = (int16_t)clampi((int)__builtin_rintf(wc * 1024.0f), -32768, 32767);
    }
  } else if (bid < 2073) {
    // embedding hi/lo split: blocks 25..2072 cover NVOCAB*DM = 524288 exactly
    int i = (bid - 25)*256 + tid;
    if (i < NVOCAB * DM) {
      int e  = clampi((int)__builtin_rintf(tok_emb[i] * 1024.0f), -32768, 32767);
      int l  = ((e + 128) & 255) - 128;   // signed low byte
      int hh = (e - l) >> 8;              // e == 256*hh + l
      if (hh > 127) hh = 127;             // unreachable for |emb| < 31.9 sigma
      elo[i] = (int8_t)l; ehi[i] = (int8_t)hh;
    }
  } else {
    // ---- embed + pre-layer-0 QKV (4 tokens per block, one per wave) ----
    int blk = bid - 2073;               // 0..1023
    int w = tid >> 6, lane = tid & 63;
    int t = blk*4 + w;                  // token 0..4095
    // layer-0 q/k/v scales, bit-identical reduction order to the prep path
    float fss[3];
    const float* srcs[3] = { qw, kw, vw };
    for (int mtx = 0; mtx < 3; mtx++) {
      const float* src = srcs[mtx];
      double s = 0.0;
      for (int i = tid; i < 4096; i += 256) s += (double)__builtin_fabsf(src[i]);
      sred[tid] = s; __syncthreads();
      for (int st = 128; st > 0; st >>= 1){ if (tid < st) sred[tid] += sred[tid + st]; __syncthreads(); }
      float fs = (float)(sred[0] / 4096.0);
      if (fs < 1e-5f) fs = 1e-5f;
      fss[mtx] = fs;
      __syncthreads();                  // sred reused next iteration
    }
    // ternarize this lane's out-row of each matrix into packed registers
    int wqr[16], wkr[16], wvr[16];
    {
      const float4* rq = (const float4*)(qw + lane*64);
      const float4* rk = (const float4*)(kw + lane*64);
      const float4* rv = (const float4*)(vw + lane*64);
      #pragma unroll
      for (int i = 0; i < 16; i++) {
        float4 f = rq[i];
        int t0 = clampi((int)__builtin_rintf(f.x / fss[0]), -1, 1);
        int t1 = clampi((int)__builtin_rintf(f.y / fss[0]), -1, 1);
        int t2 = clampi((int)__builtin_rintf(f.z / fss[0]), -1, 1);
        int t3 = clampi((int)__builtin_rintf(f.w / fss[0]), -1, 1);
        wqr[i] = (t0&255) | ((t1&255)<<8) | ((t2&255)<<16) | ((t3&255)<<24);
      }
      #pragma unroll
      for (int i = 0; i < 16; i++) {
        float4 f = rk[i];
        int t0 = clampi((int)__builtin_rintf(f.x / fss[1]), -1, 1);
        int t1 = clampi((int)__builtin_rintf(f.y / fss[1]), -1, 1);
        int t2 = clampi((int)__builtin_rintf(f.z / fss[1]), -1, 1);
        int t3 = clampi((int)__builtin_rintf(f.w / fss[1]), -1, 1);
        wkr[i] = (t0&255) | ((t1&255)<<8) | ((t2&255)<<16) | ((t3&255)<<24);
      }
      #pragma unroll
      for (int i = 0; i < 16; i++) {
        float4 f = rv[i];
        int t0 = clampi((int)__builtin_rintf(f.x / fss[2]), -1, 1);
        int t1 = clampi((int)__builtin_rintf(f.y / fss[2]), -1, 1);
        int t2 = clampi((int)__builtin_rintf(f.z / fss[2]), -1, 1);
        int t3 = clampi((int)__builtin_rintf(f.w / fss[2]), -1, 1);
        wvr[i] = (t0&255) | ((t1&255)<<8) | ((t2&255)<<16) | ((t3&255)<<24);
      }
    }
    // embed
    int tok = tokens[t];
    int s = t & (T_CTX - 1);
    int tq = clampi((int)__builtin_rintf(tok_emb[tok*DM + lane] * 1024.0f), -32768, 32767);
    int pq = clampi((int)__builtin_rintf(pos_emb[s*DM + lane] * 1024.0f), -32768, 32767);
    int xv = wrap8((tq + pq) >> 3);
    x[t*DM + lane] = (int8_t)xv;
    // layer-0 attn gamma, bit-identical to the gq path
    float gw = anw[lane];
    float gc = gw < -2.0f ? -2.0f : (gw > 2.0f ? 2.0f : gw);
    int g = clampi((int)__builtin_rintf(gc * 1024.0f), -32768, 32767);
    int h = rmsnorm_one(xv, g);
    sh_h[w][lane] = (int8_t)h;                  // wave-private row: no barrier needed
    const int* h4 = (const int*)sh_h[w];
    int b = t >> 10;
    int hh = lane >> 5, d = lane & 31;
    int bhh = b*NH + hh;
    {
      int acc = 0;
      #pragma unroll
      for (int i = 0; i < 16; i++) acc = sdot4(h4[i], wqr[i], acc);
      qA[(bhh*T_CTX + s)*HD + d] = (int8_t)clampi(acc >> 6, -128, 127);
    }
    {
      int acc = 0;
      #pragma unroll
      for (int i = 0; i < 16; i++) acc = sdot4(h4[i], wkr[i], acc);
      kA[(bhh*T_CTX + s)*HD + d] = (int8_t)clampi(acc >> 6, -128, 127);
    }
    {
      int acc = 0;
      #pragma unroll
      for (int i = 0; i < 16; i++) acc = sdot4(h4[i], wvr[i], acc);
      vT[(bhh*HD + d)*T_CTX + s] = (int8_t)clampi(acc >> 6, -128, 127);
    }
  }
}

// ---------------- fused layer: 512 threads = 4 tokens x 2 heads; V^T (both heads) XOR-swizzled in LDS ----------------
// LDS layout: vt32[64][256] linear rows (row rr = slot*32 + d); word c of row d stored at c ^ (((d>>2)&3)<<3)
//   -> staging writes land at bank (lane ^ xw): 2 lanes/bank (free)
//   -> PV reads (kc+8i)^xw across (dg,kc) lanes: 2 lanes/bank (free)
// Only 2 barriers per block: vt/probs handoff, attn-output handoff. All other LDS use is wave-private.
__global__ __launch_bounds__(512, 4) void layer_kernel(
    const int8_t* __restrict__ qA, const int8_t* __restrict__ kA, const int8_t* __restrict__ vT,
    int8_t* __restrict__ x, int8_t* __restrict__ qN, int8_t* __restrict__ kN, int8_t* __restrict__ vN,
    const int8_t* __restrict__ wt, const int16_t* __restrict__ gq, int8_t* __restrict__ xf,
    int L, int pre_layer, int do_final)
{
  __shared__ int vt32[64*256];      // 64 KB: V^T both heads, swizzled
  __shared__ int sp32[8][256];      // 8 KB: prob row per wave
  __shared__ int sh_a32[4][16];     // attn output per token
  __shared__ int8_t sh8[4][256];    // FFN temporaries (wave-private rows)

  int tid = threadIdx.x;
  int w = tid >> 6, lane = tid & 63;
  int blk = blockIdx.x;
  int b = blk & 3;
  int s0 = 1020 - 4*(blk >> 2);     // heavy (long causal) rows dispatch first
  int tl = w >> 1, h = w & 1;       // local token 0..3, head 0..1
  int qi = s0 + tl;
  int bh = b*NH + h;
  const int8_t* qBase = qA + bh*(T_CTX*HD);
  const int8_t* kBase = kA + bh*(T_CTX*HD);

  // ---- stage V^T for both heads: wave w stages rows rr = w*8 .. w*8+7 ----
  #pragma unroll
  for (int r = 0; r < 8; r++) {
    int rr = w*8 + r;
    int slot = rr >> 5, d = rr & 31;
    const int* src = (const int*)(vT + (b*NH + slot)*(HD*T_CTX) + d*T_CTX);
    int xw = ((d >> 2) & 3) << 3;
    int li = lane ^ xw;
    int* dstrow = vt32 + rr*256;
    int v0 = src[lane], v1 = src[lane+64], v2 = src[lane+128], v3 = src[lane+192];
    dstrow[li] = v0; dstrow[li+64] = v1; dstrow[li+128] = v2; dstrow[li+192] = v3;
  }

  // ---- QK^T row + hw softmax (exact) ----
  const int4* qr = (const int4*)(qBase + qi*HD);
  int4 qa = qr[0], qb = qr[1];
  int sc[16];
  int mloc = -(1 << 30);
  #pragma unroll
  for (int j = 0; j < 16; j++) {
    int k = lane + j*64;
    int s;
    if (k <= qi) {
      const int4* kr = (const int4*)(kBase + k*HD);
      int4 ka = kr[0], kb = kr[1];
      int d = 0;
      d = sdot4(qa.x, ka.x, d); d = sdot4(qa.y, ka.y, d);
      d = sdot4(qa.z, ka.z, d); d = sdot4(qa.w, ka.w, d);
      d = sdot4(qb.x, kb.x, d); d = sdot4(qb.y, kb.y, d);
      d = sdot4(qb.z, kb.z, d); d = sdot4(qb.w, kb.w, d);
      s = (d * 45) >> 8;                  // floor; diag k==q gives s>=0 so the -32767 mask never wins
    } else s = -(1 << 30);
    sc[j] = s; if (s > mloc) mloc = s;
  }
  int m = wave_reduce_max(mloc);
  int ssum = 0;
  #pragma unroll
  for (int j = 0; j < 16; j++) {
    int k = lane + j*64;
    int e = 0;
    if (k <= qi) {
      int sh = sc[j] - m;                 // <= 0
      e = (sh >= -3) ? (256 + sh*64)
        : (sh >= -8) ? (64 + (sh + 3)*11)
        : (sh >= -24) ? (sh + 24) : 0;
    }
    sc[j] = e; ssum += e;
  }
  int s0sum = wave_reduce_add(ssum); if (s0sum < 1) s0sum = 1;
  float sf = (float)s0sum;
  uint8_t* spb = (uint8_t*)sp32[w];
  #pragma unroll
  for (int j = 0; j < 16; j++) {
    int k = lane + j*64;
    // e==0 for k>qi so the same formula writes the zero padding
    int p = (int)__builtin_rintf((float)sc[j] / sf * 255.0f);
    spb[k] = (uint8_t)clampi(p, 0, 255);
  }
  __syncthreads();   // barrier #1: all waves' vt32 rows + own prob row committed

  // ---- PV via packed sdot4 from swizzled LDS: p = 2*(p>>1) + (p&1) ----
  int dg = lane & 7, kc = lane >> 3;
  int xw = (dg & 3) << 3;
  const int* vr0 = vt32 + (h*32 + dg*4 + 0)*256;
  const int* vr1 = vt32 + (h*32 + dg*4 + 1)*256;
  const int* vr2 = vt32 + (h*32 + dg*4 + 2)*256;
  const int* vr3 = vt32 + (h*32 + dg*4 + 3)*256;
  const int* spw = sp32[w];
  int hi0=0, hi1=0, hi2=0, hi3=0, lo0=0, lo1=0, lo2=0, lo3=0;
  int cmax = qi >> 2;
  for (int c = kc; c <= cmax; c += 8) {
    int p4 = spw[c];                     // 8 lanes same word -> LDS broadcast
    int cs = c ^ xw;
    int ph = (p4 >> 1) & 0x7f7f7f7f;
    int pl = p4 & 0x01010101;
    int v0 = vr0[cs], v1 = vr1[cs], v2 = vr2[cs], v3 = vr3[cs];
    hi0 = sdot4(ph, v0, hi0); lo0 = sdot4(pl, v0, lo0);
    hi1 = sdot4(ph, v1, hi1); lo1 = sdot4(pl, v1, lo1);
    hi2 = sdot4(ph, v2, hi2); lo2 = sdot4(pl, v2, lo2);
    hi3 = sdot4(ph, v3, hi3); lo3 = sdot4(pl, v3, lo3);
  }
  int a0 = 2*hi0 + lo0, a1 = 2*hi1 + lo1, a2 = 2*hi2 + lo2, a3 = 2*hi3 + lo3;
  #pragma unroll
  for (int off = 8; off < 64; off <<= 1) {
    a0 += __shfl_xor(a0, off, 64);
    a1 += __shfl_xor(a1, off, 64);
    a2 += __shfl_xor(a2, off, 64);
    a3 += __shfl_xor(a3, off, 64);
  }
  if (kc == 0) {
    int r0 = wrap8(a0 >> 8) & 255;
    int r1 = wrap8(a1 >> 8) & 255;
    int r2 = wrap8(a2 >> 8) & 255;
    int r3 = wrap8(a3 >> 8) & 255;
    int packed = r0 | (r1 << 8) | (r2 << 16) | (r3 << 24);
    sh_a32[tl][h*8 + dg] = packed;       // channel word (h*HD + dg*4)/4
  }
  __syncthreads();   // barrier #2: attn output for both heads visible

  // ---- token phase: waves 0..3 own tokens s0..s0+3; all remaining LDS use is wave-private ----
  if (w < 4) {
    int t = b*T_CTX + s0 + w;
    const int8_t* wtL = wt + L*49152;
    int xv = (int)x[t*DM + lane];
    { // o-projection, out channel = lane
      const int* a4 = sh_a32[w];
      const int* wo = (const int*)(wtL + 12288);
      int acc = 0;
      #pragma unroll
      for (int i = 0; i < 16; i++) acc = sdot4(a4[i], wo[lane*16 + i], acc);
      xv = wrap8(xv + clampi(acc >> 6, -128, 127));
    }
    int h2 = rmsnorm_one(xv, (int)gq[(4 + L)*DM + lane]);
    int8_t* myS = sh8[w];
    myS[lane] = (int8_t)h2;
    const int* h4 = (const int*)myS;
    int uv[4];
    { // up projection: 256 outputs, 4 per lane
      const int* wu = (const int*)(wtL + 16384);
      #pragma unroll
      for (int jj = 0; jj < 4; jj++) {
        int j = jj*64 + lane;
        int acc = 0;
        #pragma unroll
        for (int i = 0; i < 16; i++) acc = sdot4(h4[i], wu[j*16 + i], acc);
        int u = clampi(acc >> 6, -128, 127);
        uv[jj] = u < 0 ? 0 : u;           // relu (then int8 clamp is identity)
      }
    }
    #pragma unroll
    for (int jj = 0; jj < 4; jj++) myS[jj*64 + lane] = (int8_t)uv[jj];
    { // down projection: in-dim 256
      const int* u4 = (const int*)myS;
      const int* wd = (const int*)(wtL + 32768);
      int acc = 0;
      #pragma unroll
      for (int i = 0; i < 64; i++) acc = sdot4(u4[i], wd[lane*64 + i], acc);
      xv = wrap8(xv + clampi(acc >> 6, -128, 127));
    }
    x[t*DM + lane] = (int8_t)xv;
    if (pre_layer >= 0) {
      int hp = rmsnorm_one(xv, (int)gq[pre_layer*DM + lane]);
      myS[lane] = (int8_t)hp;
      const int* hp4 = (const int*)myS;
      const int8_t* wtP = wt + pre_layer*49152;
      int s = s0 + w;
      int hh = lane >> 5, d = lane & 31;
      int bhh = b*NH + hh;
      { // q
        const int* wm = (const int*)(wtP + 0);
        int acc = 0;
        #pragma unroll
        for (int i = 0; i < 16; i++) acc = sdot4(hp4[i], wm[lane*16 + i], acc);
        qN[(bhh*T_CTX + s)*HD + d] = (int8_t)clampi(acc >> 6, -128, 127);
      }
      { // k
        const int* wm = (const int*)(wtP + 4096);
        int acc = 0;
        #pragma unroll
        for (int i = 0; i < 16; i++) acc = sdot4(hp4[i], wm[lane*16 + i], acc);
        kN[(bhh*T_CTX + s)*HD + d] = (int8_t)clampi(acc >> 6, -128, 127);
      }
      { // v -> transposed layout
        const int* wm = (const int*)(wtP + 8192);
        int acc = 0;
        #pragma unroll
        for (int i = 0; i < 16; i++) acc = sdot4(hp4[i], wm[lane*16 + i], acc);
        vN[(bhh*HD + d)*T_CTX + s] = (int8_t)clampi(acc >> 6, -128, 127);
      }
    }
    if (do_final) {
      int hf = rmsnorm_one(xv, (int)gq[8*DM + lane]);
      xf[t*DM + lane] = (int8_t)hf;
    }
  }
}

// ---------------- logits: xf[4096x64] int8 x emb(hi/lo int8)[8192x64]^T via i8 MFMA ----------------
__global__ __launch_bounds__(256) void logits_kernel(
    const int8_t* __restrict__ xf, const int8_t* __restrict__ elo, const int8_t* __restrict__ ehi,
    float* __restrict__ out)
{
  int w = threadIdx.x >> 6, lane = threadIdx.x & 63;
  int m = lane & 15, quad = lane >> 4;
  int tokBase = blockIdx.y * 64 + w * 16;
  v4i A = *(const v4i*)(xf + (tokBase + m)*DM + quad*16);  // A[m=lane&15][k=quad*16+j]
  #pragma unroll
  for (int tile = 0; tile < 8; tile++) {
    int vocBase = blockIdx.x * 128 + tile * 16;
    v4i Blo = *(const v4i*)(elo + (vocBase + m)*DM + quad*16);
    v4i Bhi = *(const v4i*)(ehi + (vocBase + m)*DM + quad*16);
    v4i zero = {0, 0, 0, 0};
    v4i dLo = __builtin_amdgcn_mfma_i32_16x16x64_i8(A, Blo, zero, 0, 0, 0);
    v4i dHi = __builtin_amdgcn_mfma_i32_16x16x64_i8(A, Bhi, zero, 0, 0, 0);
    #pragma unroll
    for (int r = 0; r < 4; r++) {
      int val = dLo[r] + (dHi[r] << 8);                     // dot(x, 256*hi + lo), exact int32
      int row = tokBase + quad*4 + r;                       // C/D: row=(lane>>4)*4+reg
      int col = vocBase + m;                                // col=lane&15
      out[row*NVOCAB + col] = (float)val * 1.220703125e-4f; // * 2^-13 == D^-0.5/1024
    }
  }
}

extern "C" void kernel_launch(void* const* d_in, const int* in_sizes, int n_in,
                              void* d_out, int out_size, void* d_ws, size_t ws_size,
                              hipStream_t stream)
{
  const int*   tokens  = (const int*)d_in[0];
  const float* tok_emb = (const float*)d_in[1];
  const float* pos_emb = (const float*)d_in[2];
  const float* attn_nw = (const float*)d_in[3];
  const float* q_w     = (const float*)d_in[4];
  const float* k_w     = (const float*)d_in[5];
  const float* v_w     = (const float*)d_in[6];
  const float* o_w     = (const float*)d_in[7];
  const float* ff_nw   = (const float*)d_in[8];
  const float* up_w    = (const float*)d_in[9];
  const float* dn_w    = (const float*)d_in[10];
  const float* fin_nw  = (const float*)d_in[11];
  float* out = (float*)d_out;
  char* ws = (char*)d_ws;

  int8_t*  x    = (int8_t*)(ws + 0);        // 4096*64 residual stream
  int8_t*  qA0  = (int8_t*)(ws + 262144);   // [b][h][t][d] buffer 0
  int8_t*  kA0  = (int8_t*)(ws + 524288);
  int8_t*  vT0  = (int8_t*)(ws + 786432);   // [b][h][d][t]
  int8_t*  qA1  = (int8_t*)(ws + 1048576);  // buffer 1
  int8_t*  kA1  = (int8_t*)(ws + 1310720);
  int8_t*  vT1  = (int8_t*)(ws + 1572864);
  int8_t*  wt   = (int8_t*)(ws + 1835008);  // 4 layers * 49152 ternary weights
  int8_t*  elo  = (int8_t*)(ws + 2031616);  // 8192*64
  int8_t*  ehi  = (int8_t*)(ws + 2555904);  // 8192*64
  int16_t* gq   = (int16_t*)(ws + 3080192); // 9*64
  int8_t*  xf   = (int8_t*)(ws + 3081344);  // 4096*64

  prep_embed<<<3097, 256, 0, stream>>>(tokens, tok_emb, pos_emb,
                                       q_w, k_w, v_w, o_w, up_w, dn_w, attn_nw, ff_nw, fin_nw,
                                       wt, gq, elo, ehi, x, qA0, kA0, vT0);
  for (int L = 0; L < 4; L++) {
    int8_t* qC = (L & 1) ? qA1 : qA0;  int8_t* qX = (L & 1) ? qA0 : qA1;
    int8_t* kC = (L & 1) ? kA1 : kA0;  int8_t* kX = (L & 1) ? kA0 : kA1;
    int8_t* vC = (L & 1) ? vT1 : vT0;  int8_t* vX = (L & 1) ? vT0 : vT1;
    int pre = (L < 3) ? (L + 1) : -1;
    int fin = (L == 3) ? 1 : 0;
    layer_kernel<<<1024, 512, 0, stream>>>(qC, kC, vC, x, qX, kX, vX, wt, gq, xf, L, pre, fin);
  }
  logits_kernel<<<dim3(64, 64), 256, 0, stream>>>(xf, elo, ehi, out);
}

// Round 5
// 343.538 us; speedup vs baseline: 2.6867x; 1.0415x over previous
//
#include <hip/hip_runtime.h>
#include <stdint.h>

#define T_CTX 1024
#define DM 64
#define NH 2
#define HD 32
#define DFF 256
#define NVOCAB 8192

typedef int v4i __attribute__((ext_vector_type(4)));

__device__ __forceinline__ int clampi(int v, int lo, int hi){ return v<lo?lo:(v>hi?hi:v); }
__device__ __forceinline__ int wrap8(int v){ return ((v + 128) & 255) - 128; }
__device__ __forceinline__ int sdot4(int a, int b, int c){ return __builtin_amdgcn_sdot4(a, b, c, false); }

__device__ __forceinline__ int wave_reduce_add(int v){
  #pragma unroll
  for (int off = 1; off < 64; off <<= 1) v += __shfl_xor(v, off, 64);
  return v;
}
__device__ __forceinline__ int wave_reduce_max(int v){
  #pragma unroll
  for (int off = 1; off < 64; off <<= 1){ int o = __shfl_xor(v, off, 64); v = o > v ? o : v; }
  return v;
}

// rmsnorm_hw forward: exact integer pipeline; lane == channel (wave64 == DM)
__device__ __forceinline__ int rmsnorm_one(int xv, int g){
  int ss  = wave_reduce_add(xv * xv);
  int ms  = ss >> 6;                 // /64 == /d_model
  int lut = ms >> 6; if (lut > 255) lut = 255;
  int bc  = lut * 64 + 32;           // >= 32, so max(.,1) vacuous
  int inv = (int)__builtin_rint(16384.0 / __builtin_sqrt((double)bc)); // <= 2897 < 16383
  int p1  = (xv * inv) >> 8;         // arithmetic shift == floor
  int y   = (p1 * g) >> 10;
  return clampi(y, -128, 127);
}

// ---------------- prep + embed fused (block-range split; halves are independent) ----------------
// bid 0..23   : ternarize weights -> wt
// bid 24      : quantize 9 norm gammas -> gq
// bid 25..2072: split Q5.10 embedding into hi/lo planes
// bid 2073..2584: embed 8 tokens/block + layer-0 QKV (scales recomputed bit-identically once per block)
__global__ __launch_bounds__(256) void prep_embed(
    const int* __restrict__ tokens, const float* __restrict__ tok_emb, const float* __restrict__ pos_emb,
    const float* __restrict__ qw, const float* __restrict__ kw, const float* __restrict__ vw,
    const float* __restrict__ ow, const float* __restrict__ uw, const float* __restrict__ dw,
    const float* __restrict__ anw, const float* __restrict__ fnw, const float* __restrict__ finw,
    int8_t* __restrict__ wt, int16_t* __restrict__ gq,
    int8_t* __restrict__ elo, int8_t* __restrict__ ehi,
    int8_t* __restrict__ x, int8_t* __restrict__ qA, int8_t* __restrict__ kA, int8_t* __restrict__ vT)
{
  __shared__ double sred[256];
  __shared__ int8_t sh_h[4][64];
  int tid = threadIdx.x, bid = blockIdx.x;
  if (bid < 24) {
    int layer = bid / 6, kind = bid % 6;
    const float* src; int n; int off;
    switch (kind) {
      case 0:  src = qw + layer*4096;  n = 4096;  off = 0;     break;
      case 1:  src = kw + layer*4096;  n = 4096;  off = 4096;  break;
      case 2:  src = vw + layer*4096;  n = 4096;  off = 8192;  break;
      case 3:  src = ow + layer*4096;  n = 4096;  off = 12288; break;
      case 4:  src = uw + layer*16384; n = 16384; off = 16384; break;
      default: src = dw + layer*16384; n = 16384; off = 32768; break;
    }
    double s = 0.0;
    for (int i = tid; i < n; i += 256) s += (double)__builtin_fabsf(src[i]);
    sred[tid] = s; __syncthreads();
    for (int st = 128; st > 0; st >>= 1){ if (tid < st) sred[tid] += sred[tid + st]; __syncthreads(); }
    float fs = (float)(sred[0] / (double)n);
    if (fs < 1e-5f) fs = 1e-5f;
    int8_t* dst = wt + layer*49152 + off;
    for (int i = tid; i < n; i += 256) {
      int t = (int)__builtin_rintf(src[i] / fs);
      dst[i] = (int8_t)clampi(t, -1, 1);
    }
  } else if (bid == 24) {
    // 9 norms x 64 channels: 0..3 attn, 4..7 ffn, 8 final
    for (int i = tid; i < 576; i += 256) {
      int norm = i >> 6, c = i & 63;
      const float* wsrc = (norm < 4) ? (anw + norm*64) : (norm < 8) ? (fnw + (norm-4)*64) : finw;
      float wv = wsrc[c];
      float wc = wv < -2.0f ? -2.0f : (wv > 2.0f ? 2.0f : wv);
      gq[i] = (int16_t)clampi((int)__builtin_rintf(wc * 1024.0f), -32768, 32767);
    }
  } else if (bid < 2073) {
    // embedding hi/lo split: blocks 25..2072 cover NVOCAB*DM = 524288 exactly
    int i = (bid - 25)*256 + tid;
    if (i < NVOCAB * DM) {
      int e  = clampi((int)__builtin_rintf(tok_emb[i] * 1024.0f), -32768, 32767);
      int l  = ((e + 128) & 255) - 128;   // signed low byte
      int hh = (e - l) >> 8;              // e == 256*hh + l
      if (hh > 127) hh = 127;             // unreachable for |emb| < 31.9 sigma
      elo[i] = (int8_t)l; ehi[i] = (int8_t)hh;
    }
  } else {
    // ---- embed + pre-layer-0 QKV: 8 tokens per block (2 passes x 4 waves) ----
    int blk = bid - 2073;               // 0..511
    int w = tid >> 6, lane = tid & 63;
    // layer-0 q/k/v scales, bit-identical reduction order to the prep path
    float fss[3];
    const float* srcs[3] = { qw, kw, vw };
    for (int mtx = 0; mtx < 3; mtx++) {
      const float* src = srcs[mtx];
      double s = 0.0;
      for (int i = tid; i < 4096; i += 256) s += (double)__builtin_fabsf(src[i]);
      sred[tid] = s; __syncthreads();
      for (int st = 128; st > 0; st >>= 1){ if (tid < st) sred[tid] += sred[tid + st]; __syncthreads(); }
      float fs = (float)(sred[0] / 4096.0);
      if (fs < 1e-5f) fs = 1e-5f;
      fss[mtx] = fs;
      __syncthreads();                  // sred reused next iteration
    }
    // ternarize this lane's out-row of each matrix into packed registers (once per block)
    int wqr[16], wkr[16], wvr[16];
    {
      const float4* rq = (const float4*)(qw + lane*64);
      const float4* rk = (const float4*)(kw + lane*64);
      const float4* rv = (const float4*)(vw + lane*64);
      #pragma unroll
      for (int i = 0; i < 16; i++) {
        float4 f = rq[i];
        int t0 = clampi((int)__builtin_rintf(f.x / fss[0]), -1, 1);
        int t1 = clampi((int)__builtin_rintf(f.y / fss[0]), -1, 1);
        int t2 = clampi((int)__builtin_rintf(f.z / fss[0]), -1, 1);
        int t3 = clampi((int)__builtin_rintf(f.w / fss[0]), -1, 1);
        wqr[i] = (t0&255) | ((t1&255)<<8) | ((t2&255)<<16) | ((t3&255)<<24);
      }
      #pragma unroll
      for (int i = 0; i < 16; i++) {
        float4 f = rk[i];
        int t0 = clampi((int)__builtin_rintf(f.x / fss[1]), -1, 1);
        int t1 = clampi((int)__builtin_rintf(f.y / fss[1]), -1, 1);
        int t2 = clampi((int)__builtin_rintf(f.z / fss[1]), -1, 1);
        int t3 = clampi((int)__builtin_rintf(f.w / fss[1]), -1, 1);
        wkr[i] = (t0&255) | ((t1&255)<<8) | ((t2&255)<<16) | ((t3&255)<<24);
      }
      #pragma unroll
      for (int i = 0; i < 16; i++) {
        float4 f = rv[i];
        int t0 = clampi((int)__builtin_rintf(f.x / fss[2]), -1, 1);
        int t1 = clampi((int)__builtin_rintf(f.y / fss[2]), -1, 1);
        int t2 = clampi((int)__builtin_rintf(f.z / fss[2]), -1, 1);
        int t3 = clampi((int)__builtin_rintf(f.w / fss[2]), -1, 1);
        wvr[i] = (t0&255) | ((t1&255)<<8) | ((t2&255)<<16) | ((t3&255)<<24);
      }
    }
    // layer-0 attn gamma, bit-identical to the gq path
    float gw = anw[lane];
    float gc = gw < -2.0f ? -2.0f : (gw > 2.0f ? 2.0f : gw);
    int g = clampi((int)__builtin_rintf(gc * 1024.0f), -32768, 32767);
    #pragma unroll
    for (int pass = 0; pass < 2; pass++) {
      int t = blk*8 + pass*4 + w;       // token 0..4095
      int tok = tokens[t];
      int s = t & (T_CTX - 1);
      int tq = clampi((int)__builtin_rintf(tok_emb[tok*DM + lane] * 1024.0f), -32768, 32767);
      int pq = clampi((int)__builtin_rintf(pos_emb[s*DM + lane] * 1024.0f), -32768, 32767);
      int xv = wrap8((tq + pq) >> 3);
      x[t*DM + lane] = (int8_t)xv;
      int h = rmsnorm_one(xv, g);
      sh_h[w][lane] = (int8_t)h;                  // wave-private row: no barrier needed
      const int* h4 = (const int*)sh_h[w];
      int b = t >> 10;
      int hh = lane >> 5, d = lane & 31;
      int bhh = b*NH + hh;
      {
        int acc = 0;
        #pragma unroll
        for (int i = 0; i < 16; i++) acc = sdot4(h4[i], wqr[i], acc);
        qA[(bhh*T_CTX + s)*HD + d] = (int8_t)clampi(acc >> 6, -128, 127);
      }
      {
        int acc = 0;
        #pragma unroll
        for (int i = 0; i < 16; i++) acc = sdot4(h4[i], wkr[i], acc);
        kA[(bhh*T_CTX + s)*HD + d] = (int8_t)clampi(acc >> 6, -128, 127);
      }
      {
        int acc = 0;
        #pragma unroll
        for (int i = 0; i < 16; i++) acc = sdot4(h4[i], wvr[i], acc);
        vT[(bhh*HD + d)*T_CTX + s] = (int8_t)clampi(acc >> 6, -128, 127);
      }
    }
  }
}

// ---------------- fused layer: 512 threads = 4 tokens x 2 heads; V^T (both heads) XOR-swizzled in LDS ----------------
// LDS layout: vt32[64][256] linear rows (row rr = slot*32 + d); word c of row d stored at c ^ (((d>>2)&3)<<3)
//   -> staging writes land at bank (lane ^ xw): 2 lanes/bank (free)
//   -> PV reads (kc+8i)^xw across (dg,kc) lanes: 2 lanes/bank (free)
// Only 2 barriers per block: vt/probs handoff, attn-output handoff. All other LDS use is wave-private.
__global__ __launch_bounds__(512, 4) void layer_kernel(
    const int8_t* __restrict__ qA, const int8_t* __restrict__ kA, const int8_t* __restrict__ vT,
    int8_t* __restrict__ x, int8_t* __restrict__ qN, int8_t* __restrict__ kN, int8_t* __restrict__ vN,
    const int8_t* __restrict__ wt, const int16_t* __restrict__ gq, int8_t* __restrict__ xf,
    int L, int pre_layer, int do_final)
{
  __shared__ int vt32[64*256];      // 64 KB: V^T both heads, swizzled
  __shared__ int sp32[8][256];      // 8 KB: prob row per wave
  __shared__ int sh_a32[4][16];     // attn output per token
  __shared__ int8_t sh8[4][256];    // FFN temporaries (wave-private rows)

  int tid = threadIdx.x;
  int w = tid >> 6, lane = tid & 63;
  int blk = blockIdx.x;
  int b = blk & 3;
  int s0 = 1020 - 4*(blk >> 2);     // heavy (long causal) rows dispatch first
  int tl = w >> 1, h = w & 1;       // local token 0..3, head 0..1
  int qi = s0 + tl;
  int bh = b*NH + h;
  const int8_t* qBase = qA + bh*(T_CTX*HD);
  const int8_t* kBase = kA + bh*(T_CTX*HD);

  // ---- stage V^T for both heads: wave w stages rows rr = w*8 .. w*8+7 ----
  #pragma unroll
  for (int r = 0; r < 8; r++) {
    int rr = w*8 + r;
    int slot = rr >> 5, d = rr & 31;
    const int* src = (const int*)(vT + (b*NH + slot)*(HD*T_CTX) + d*T_CTX);
    int xw = ((d >> 2) & 3) << 3;
    int li = lane ^ xw;
    int* dstrow = vt32 + rr*256;
    int v0 = src[lane], v1 = src[lane+64], v2 = src[lane+128], v3 = src[lane+192];
    dstrow[li] = v0; dstrow[li+64] = v1; dstrow[li+128] = v2; dstrow[li+192] = v3;
  }

  // ---- QK^T row + hw softmax (exact) ----
  const int4* qr = (const int4*)(qBase + qi*HD);
  int4 qa = qr[0], qb = qr[1];
  int sc[16];
  int mloc = -(1 << 30);
  #pragma unroll
  for (int j = 0; j < 16; j++) {
    int k = lane + j*64;
    int s;
    if (k <= qi) {
      const int4* kr = (const int4*)(kBase + k*HD);
      int4 ka = kr[0], kb = kr[1];
      int d = 0;
      d = sdot4(qa.x, ka.x, d); d = sdot4(qa.y, ka.y, d);
      d = sdot4(qa.z, ka.z, d); d = sdot4(qa.w, ka.w, d);
      d = sdot4(qb.x, kb.x, d); d = sdot4(qb.y, kb.y, d);
      d = sdot4(qb.z, kb.z, d); d = sdot4(qb.w, kb.w, d);
      s = (d * 45) >> 8;                  // floor; diag k==q gives s>=0 so the -32767 mask never wins
    } else s = -(1 << 30);
    sc[j] = s; if (s > mloc) mloc = s;
  }
  int m = wave_reduce_max(mloc);
  int ssum = 0;
  #pragma unroll
  for (int j = 0; j < 16; j++) {
    int k = lane + j*64;
    int e = 0;
    if (k <= qi) {
      int sh = sc[j] - m;                 // <= 0
      e = (sh >= -3) ? (256 + sh*64)
        : (sh >= -8) ? (64 + (sh + 3)*11)
        : (sh >= -24) ? (sh + 24) : 0;
    }
    sc[j] = e; ssum += e;
  }
  int s0sum = wave_reduce_add(ssum); if (s0sum < 1) s0sum = 1;
  float sf = (float)s0sum;
  uint8_t* spb = (uint8_t*)sp32[w];
  #pragma unroll
  for (int j = 0; j < 16; j++) {
    int k = lane + j*64;
    // e==0 for k>qi so the same formula writes the zero padding
    int p = (int)__builtin_rintf((float)sc[j] / sf * 255.0f);
    spb[k] = (uint8_t)clampi(p, 0, 255);
  }
  __syncthreads();   // barrier #1: all waves' vt32 rows + own prob row committed

  // ---- PV via packed sdot4 from swizzled LDS: p = 2*(p>>1) + (p&1) ----
  int dg = lane & 7, kc = lane >> 3;
  int xw = (dg & 3) << 3;
  const int* vr0 = vt32 + (h*32 + dg*4 + 0)*256;
  const int* vr1 = vt32 + (h*32 + dg*4 + 1)*256;
  const int* vr2 = vt32 + (h*32 + dg*4 + 2)*256;
  const int* vr3 = vt32 + (h*32 + dg*4 + 3)*256;
  const int* spw = sp32[w];
  int hi0=0, hi1=0, hi2=0, hi3=0, lo0=0, lo1=0, lo2=0, lo3=0;
  int cmax = qi >> 2;
  for (int c = kc; c <= cmax; c += 8) {
    int p4 = spw[c];                     // 8 lanes same word -> LDS broadcast
    int cs = c ^ xw;
    int ph = (p4 >> 1) & 0x7f7f7f7f;
    int pl = p4 & 0x01010101;
    int v0 = vr0[cs], v1 = vr1[cs], v2 = vr2[cs], v3 = vr3[cs];
    hi0 = sdot4(ph, v0, hi0); lo0 = sdot4(pl, v0, lo0);
    hi1 = sdot4(ph, v1, hi1); lo1 = sdot4(pl, v1, lo1);
    hi2 = sdot4(ph, v2, hi2); lo2 = sdot4(pl, v2, lo2);
    hi3 = sdot4(ph, v3, hi3); lo3 = sdot4(pl, v3, lo3);
  }
  int a0 = 2*hi0 + lo0, a1 = 2*hi1 + lo1, a2 = 2*hi2 + lo2, a3 = 2*hi3 + lo3;
  #pragma unroll
  for (int off = 8; off < 64; off <<= 1) {
    a0 += __shfl_xor(a0, off, 64);
    a1 += __shfl_xor(a1, off, 64);
    a2 += __shfl_xor(a2, off, 64);
    a3 += __shfl_xor(a3, off, 64);
  }
  if (kc == 0) {
    int r0 = wrap8(a0 >> 8) & 255;
    int r1 = wrap8(a1 >> 8) & 255;
    int r2 = wrap8(a2 >> 8) & 255;
    int r3 = wrap8(a3 >> 8) & 255;
    int packed = r0 | (r1 << 8) | (r2 << 16) | (r3 << 24);
    sh_a32[tl][h*8 + dg] = packed;       // channel word (h*HD + dg*4)/4
  }
  __syncthreads();   // barrier #2: attn output for both heads visible

  // ---- token phase: waves 0..3 own tokens s0..s0+3; all remaining LDS use is wave-private ----
  if (w < 4) {
    int t = b*T_CTX + s0 + w;
    const int8_t* wtL = wt + L*49152;
    int xv = (int)x[t*DM + lane];
    { // o-projection, out channel = lane
      const int* a4 = sh_a32[w];
      const int* wo = (const int*)(wtL + 12288);
      int acc = 0;
      #pragma unroll
      for (int i = 0; i < 16; i++) acc = sdot4(a4[i], wo[lane*16 + i], acc);
      xv = wrap8(xv + clampi(acc >> 6, -128, 127));
    }
    int h2 = rmsnorm_one(xv, (int)gq[(4 + L)*DM + lane]);
    int8_t* myS = sh8[w];
    myS[lane] = (int8_t)h2;
    const int* h4 = (const int*)myS;
    int uv[4];
    { // up projection: 256 outputs, 4 per lane
      const int* wu = (const int*)(wtL + 16384);
      #pragma unroll
      for (int jj = 0; jj < 4; jj++) {
        int j = jj*64 + lane;
        int acc = 0;
        #pragma unroll
        for (int i = 0; i < 16; i++) acc = sdot4(h4[i], wu[j*16 + i], acc);
        int u = clampi(acc >> 6, -128, 127);
        uv[jj] = u < 0 ? 0 : u;           // relu (then int8 clamp is identity)
      }
    }
    #pragma unroll
    for (int jj = 0; jj < 4; jj++) myS[jj*64 + lane] = (int8_t)uv[jj];
    { // down projection: in-dim 256
      const int* u4 = (const int*)myS;
      const int* wd = (const int*)(wtL + 32768);
      int acc = 0;
      #pragma unroll
      for (int i = 0; i < 64; i++) acc = sdot4(u4[i], wd[lane*64 + i], acc);
      xv = wrap8(xv + clampi(acc >> 6, -128, 127));
    }
    x[t*DM + lane] = (int8_t)xv;
    if (pre_layer >= 0) {
      int hp = rmsnorm_one(xv, (int)gq[pre_layer*DM + lane]);
      myS[lane] = (int8_t)hp;
      const int* hp4 = (const int*)myS;
      const int8_t* wtP = wt + pre_layer*49152;
      int s = s0 + w;
      int hh = lane >> 5, d = lane & 31;
      int bhh = b*NH + hh;
      { // q
        const int* wm = (const int*)(wtP + 0);
        int acc = 0;
        #pragma unroll
        for (int i = 0; i < 16; i++) acc = sdot4(hp4[i], wm[lane*16 + i], acc);
        qN[(bhh*T_CTX + s)*HD + d] = (int8_t)clampi(acc >> 6, -128, 127);
      }
      { // k
        const int* wm = (const int*)(wtP + 4096);
        int acc = 0;
        #pragma unroll
        for (int i = 0; i < 16; i++) acc = sdot4(hp4[i], wm[lane*16 + i], acc);
        kN[(bhh*T_CTX + s)*HD + d] = (int8_t)clampi(acc >> 6, -128, 127);
      }
      { // v -> transposed layout
        const int* wm = (const int*)(wtP + 8192);
        int acc = 0;
        #pragma unroll
        for (int i = 0; i < 16; i++) acc = sdot4(hp4[i], wm[lane*16 + i], acc);
        vN[(bhh*HD + d)*T_CTX + s] = (int8_t)clampi(acc >> 6, -128, 127);
      }
    }
    if (do_final) {
      int hf = rmsnorm_one(xv, (int)gq[8*DM + lane]);
      xf[t*DM + lane] = (int8_t)hf;
    }
  }
}

// ---------------- logits: swapped-operand i8 MFMA -> D[vocab][token], float4 stores ----------------
// A = emb tile (vocab rows), B = xf tile (token cols). D row = vocab = quad*4+r (consecutive per lane),
// D col = token = lane&15 -> each lane packs 4 consecutive vocab logits of one token into one dwordx4 store.
__global__ __launch_bounds__(256) void logits_kernel(
    const int8_t* __restrict__ xf, const int8_t* __restrict__ elo, const int8_t* __restrict__ ehi,
    float* __restrict__ out)
{
  int w = threadIdx.x >> 6, lane = threadIdx.x & 63;
  int m = lane & 15, quad = lane >> 4;
  int tokBase = blockIdx.y * 64 + w * 16;
  v4i Bx = *(const v4i*)(xf + (tokBase + m)*DM + quad*16);   // B[k=quad*16+j][n=m(token)]
  float* orow = out + (tokBase + m)*NVOCAB;
  #pragma unroll
  for (int tile = 0; tile < 8; tile++) {
    int vocBase = blockIdx.x * 128 + tile * 16;
    v4i Alo = *(const v4i*)(elo + (vocBase + m)*DM + quad*16);  // A[m'=vocab row][k]
    v4i Ahi = *(const v4i*)(ehi + (vocBase + m)*DM + quad*16);
    v4i zero = {0, 0, 0, 0};
    v4i dLo = __builtin_amdgcn_mfma_i32_16x16x64_i8(Alo, Bx, zero, 0, 0, 0);
    v4i dHi = __builtin_amdgcn_mfma_i32_16x16x64_i8(Ahi, Bx, zero, 0, 0, 0);
    float4 o;
    o.x = (float)(dLo[0] + (dHi[0] << 8)) * 1.220703125e-4f;  // * 2^-13 == D^-0.5/1024
    o.y = (float)(dLo[1] + (dHi[1] << 8)) * 1.220703125e-4f;
    o.z = (float)(dLo[2] + (dHi[2] << 8)) * 1.220703125e-4f;
    o.w = (float)(dLo[3] + (dHi[3] << 8)) * 1.220703125e-4f;
    *(float4*)(orow + vocBase + quad*4) = o;                  // 16 B per lane, 4x fewer stores
  }
}

extern "C" void kernel_launch(void* const* d_in, const int* in_sizes, int n_in,
                              void* d_out, int out_size, void* d_ws, size_t ws_size,
                              hipStream_t stream)
{
  const int*   tokens  = (const int*)d_in[0];
  const float* tok_emb = (const float*)d_in[1];
  const float* pos_emb = (const float*)d_in[2];
  const float* attn_nw = (const float*)d_in[3];
  const float* q_w     = (const float*)d_in[4];
  const float* k_w     = (const float*)d_in[5];
  const float* v_w     = (const float*)d_in[6];
  const float* o_w     = (const float*)d_in[7];
  const float* ff_nw   = (const float*)d_in[8];
  const float* up_w    = (const float*)d_in[9];
  const float* dn_w    = (const float*)d_in[10];
  const float* fin_nw  = (const float*)d_in[11];
  float* out = (float*)d_out;
  char* ws = (char*)d_ws;

  int8_t*  x    = (int8_t*)(ws + 0);        // 4096*64 residual stream
  int8_t*  qA0  = (int8_t*)(ws + 262144);   // [b][h][t][d] buffer 0
  int8_t*  kA0  = (int8_t*)(ws + 524288);
  int8_t*  vT0  = (int8_t*)(ws + 786432);   // [b][h][d][t]
  int8_t*  qA1  = (int8_t*)(ws + 1048576);  // buffer 1
  int8_t*  kA1  = (int8_t*)(ws + 1310720);
  int8_t*  vT1  = (int8_t*)(ws + 1572864);
  int8_t*  wt   = (int8_t*)(ws + 1835008);  // 4 layers * 49152 ternary weights
  int8_t*  elo  = (int8_t*)(ws + 2031616);  // 8192*64
  int8_t*  ehi  = (int8_t*)(ws + 2555904);  // 8192*64
  int16_t* gq   = (int16_t*)(ws + 3080192); // 9*64
  int8_t*  xf   = (int8_t*)(ws + 3081344);  // 4096*64

  prep_embed<<<2585, 256, 0, stream>>>(tokens, tok_emb, pos_emb,
                                       q_w, k_w, v_w, o_w, up_w, dn_w, attn_nw, ff_nw, fin_nw,
                                       wt, gq, elo, ehi, x, qA0, kA0, vT0);
  for (int L = 0; L < 4; L++) {
    int8_t* qC = (L & 1) ? qA1 : qA0;  int8_t* qX = (L & 1) ? qA0 : qA1;
    int8_t* kC = (L & 1) ? kA1 : kA0;  int8_t* kX = (L & 1) ? kA0 : kA1;
    int8_t* vC = (L & 1) ? vT1 : vT0;  int8_t* vX = (L & 1) ? vT0 : vT1;
    int pre = (L < 3) ? (L + 1) : -1;
    int fin = (L == 3) ? 1 : 0;
    layer_kernel<<<1024, 512, 0, stream>>>(qC, kC, vC, x, qX, kX, vX, wt, gq, xf, L, pre, fin);
  }
  logits_kernel<<<dim3(64, 64), 256, 0, stream>>>(xf, elo, ehi, out);
}

// Round 6
// 325.096 us; speedup vs baseline: 2.8391x; 1.0567x over previous
//
#include <hip/hip_runtime.h>
#include <stdint.h>

#define T_CTX 1024
#define DM 64
#define NH 2
#define HD 32
#define DFF 256
#define NVOCAB 8192

typedef int v4i __attribute__((ext_vector_type(4)));

__device__ __forceinline__ int clampi(int v, int lo, int hi){ return v<lo?lo:(v>hi?hi:v); }
__device__ __forceinline__ int wrap8(int v){ return ((v + 128) & 255) - 128; }
__device__ __forceinline__ int sdot4(int a, int b, int c){ return __builtin_amdgcn_sdot4(a, b, c, false); }

__device__ __forceinline__ int wave_reduce_add(int v){
  #pragma unroll
  for (int off = 1; off < 64; off <<= 1) v += __shfl_xor(v, off, 64);
  return v;
}
__device__ __forceinline__ int wave_reduce_max(int v){
  #pragma unroll
  for (int off = 1; off < 64; off <<= 1){ int o = __shfl_xor(v, off, 64); v = o > v ? o : v; }
  return v;
}

// rmsnorm_hw forward: exact integer pipeline; lane == channel (wave64 == DM)
__device__ __forceinline__ int rmsnorm_one(int xv, int g){
  int ss  = wave_reduce_add(xv * xv);
  int ms  = ss >> 6;                 // /64 == /d_model
  int lut = ms >> 6; if (lut > 255) lut = 255;
  int bc  = lut * 64 + 32;           // >= 32, so max(.,1) vacuous
  int inv = (int)__builtin_rint(16384.0 / __builtin_sqrt((double)bc)); // <= 2897 < 16383
  int p1  = (xv * inv) >> 8;         // arithmetic shift == floor
  int y   = (p1 * g) >> 10;
  return clampi(y, -128, 127);
}

// ---------------- prep + embed fused (block-range split; halves are independent) ----------------
// bid 0..23  : ternarize weights -> wt
// bid 24     : quantize 9 norm gammas -> gq
// bid 25..536: split Q5.10 embedding into hi/lo planes (float4-vectorized, 4 elems/thread)
// bid 537..1048: embed 8 tokens/block + layer-0 QKV (scales recomputed bit-identically once per block)
__global__ __launch_bounds__(256) void prep_embed(
    const int* __restrict__ tokens, const float* __restrict__ tok_emb, const float* __restrict__ pos_emb,
    const float* __restrict__ qw, const float* __restrict__ kw, const float* __restrict__ vw,
    const float* __restrict__ ow, const float* __restrict__ uw, const float* __restrict__ dw,
    const float* __restrict__ anw, const float* __restrict__ fnw, const float* __restrict__ finw,
    int8_t* __restrict__ wt, int16_t* __restrict__ gq,
    int8_t* __restrict__ elo, int8_t* __restrict__ ehi,
    int8_t* __restrict__ x, int8_t* __restrict__ qA, int8_t* __restrict__ kA, int8_t* __restrict__ vT)
{
  __shared__ double sred[256];
  __shared__ int8_t sh_h[4][64];
  int tid = threadIdx.x, bid = blockIdx.x;
  if (bid < 24) {
    int layer = bid / 6, kind = bid % 6;
    const float* src; int n; int off;
    switch (kind) {
      case 0:  src = qw + layer*4096;  n = 4096;  off = 0;     break;
      case 1:  src = kw + layer*4096;  n = 4096;  off = 4096;  break;
      case 2:  src = vw + layer*4096;  n = 4096;  off = 8192;  break;
      case 3:  src = ow + layer*4096;  n = 4096;  off = 12288; break;
      case 4:  src = uw + layer*16384; n = 16384; off = 16384; break;
      default: src = dw + layer*16384; n = 16384; off = 32768; break;
    }
    double s = 0.0;
    for (int i = tid; i < n; i += 256) s += (double)__builtin_fabsf(src[i]);
    sred[tid] = s; __syncthreads();
    for (int st = 128; st > 0; st >>= 1){ if (tid < st) sred[tid] += sred[tid + st]; __syncthreads(); }
    float fs = (float)(sred[0] / (double)n);
    if (fs < 1e-5f) fs = 1e-5f;
    int8_t* dst = wt + layer*49152 + off;
    for (int i = tid; i < n; i += 256) {
      int t = (int)__builtin_rintf(src[i] / fs);
      dst[i] = (int8_t)clampi(t, -1, 1);
    }
  } else if (bid == 24) {
    // 9 norms x 64 channels: 0..3 attn, 4..7 ffn, 8 final
    for (int i = tid; i < 576; i += 256) {
      int norm = i >> 6, c = i & 63;
      const float* wsrc = (norm < 4) ? (anw + norm*64) : (norm < 8) ? (fnw + (norm-4)*64) : finw;
      float wv = wsrc[c];
      float wc = wv < -2.0f ? -2.0f : (wv > 2.0f ? 2.0f : wv);
      gq[i] = (int16_t)clampi((int)__builtin_rintf(wc * 1024.0f), -32768, 32767);
    }
  } else if (bid < 537) {
    // embedding hi/lo split: 512 blocks x 256 threads x 4 elems = 524288 exactly
    int i4 = (bid - 25)*1024 + tid*4;
    float4 f = *(const float4*)(tok_emb + i4);
    int e0 = clampi((int)__builtin_rintf(f.x * 1024.0f), -32768, 32767);
    int e1 = clampi((int)__builtin_rintf(f.y * 1024.0f), -32768, 32767);
    int e2 = clampi((int)__builtin_rintf(f.z * 1024.0f), -32768, 32767);
    int e3 = clampi((int)__builtin_rintf(f.w * 1024.0f), -32768, 32767);
    int l0 = ((e0 + 128) & 255) - 128, l1 = ((e1 + 128) & 255) - 128;
    int l2 = ((e2 + 128) & 255) - 128, l3 = ((e3 + 128) & 255) - 128;
    int h0 = (e0 - l0) >> 8, h1 = (e1 - l1) >> 8;  // |e|<=32767 -> hi in [-128,127], no clamp needed
    int h2 = (e2 - l2) >> 8, h3 = (e3 - l3) >> 8;
    *(int*)(elo + i4) = (l0&255) | ((l1&255)<<8) | ((l2&255)<<16) | ((l3&255)<<24);
    *(int*)(ehi + i4) = (h0&255) | ((h1&255)<<8) | ((h2&255)<<16) | ((h3&255)<<24);
  } else {
    // ---- embed + pre-layer-0 QKV: 8 tokens per block (2 passes x 4 waves) ----
    int blk = bid - 537;                // 0..511
    int w = tid >> 6, lane = tid & 63;
    // layer-0 q/k/v scales, bit-identical reduction order to the prep path
    float fss[3];
    const float* srcs[3] = { qw, kw, vw };
    for (int mtx = 0; mtx < 3; mtx++) {
      const float* src = srcs[mtx];
      double s = 0.0;
      for (int i = tid; i < 4096; i += 256) s += (double)__builtin_fabsf(src[i]);
      sred[tid] = s; __syncthreads();
      for (int st = 128; st > 0; st >>= 1){ if (tid < st) sred[tid] += sred[tid + st]; __syncthreads(); }
      float fs = (float)(sred[0] / 4096.0);
      if (fs < 1e-5f) fs = 1e-5f;
      fss[mtx] = fs;
      __syncthreads();                  // sred reused next iteration
    }
    // ternarize this lane's out-row of each matrix into packed registers (once per block)
    int wqr[16], wkr[16], wvr[16];
    {
      const float4* rq = (const float4*)(qw + lane*64);
      const float4* rk = (const float4*)(kw + lane*64);
      const float4* rv = (const float4*)(vw + lane*64);
      #pragma unroll
      for (int i = 0; i < 16; i++) {
        float4 f = rq[i];
        int t0 = clampi((int)__builtin_rintf(f.x / fss[0]), -1, 1);
        int t1 = clampi((int)__builtin_rintf(f.y / fss[0]), -1, 1);
        int t2 = clampi((int)__builtin_rintf(f.z / fss[0]), -1, 1);
        int t3 = clampi((int)__builtin_rintf(f.w / fss[0]), -1, 1);
        wqr[i] = (t0&255) | ((t1&255)<<8) | ((t2&255)<<16) | ((t3&255)<<24);
      }
      #pragma unroll
      for (int i = 0; i < 16; i++) {
        float4 f = rk[i];
        int t0 = clampi((int)__builtin_rintf(f.x / fss[1]), -1, 1);
        int t1 = clampi((int)__builtin_rintf(f.y / fss[1]), -1, 1);
        int t2 = clampi((int)__builtin_rintf(f.z / fss[1]), -1, 1);
        int t3 = clampi((int)__builtin_rintf(f.w / fss[1]), -1, 1);
        wkr[i] = (t0&255) | ((t1&255)<<8) | ((t2&255)<<16) | ((t3&255)<<24);
      }
      #pragma unroll
      for (int i = 0; i < 16; i++) {
        float4 f = rv[i];
        int t0 = clampi((int)__builtin_rintf(f.x / fss[2]), -1, 1);
        int t1 = clampi((int)__builtin_rintf(f.y / fss[2]), -1, 1);
        int t2 = clampi((int)__builtin_rintf(f.z / fss[2]), -1, 1);
        int t3 = clampi((int)__builtin_rintf(f.w / fss[2]), -1, 1);
        wvr[i] = (t0&255) | ((t1&255)<<8) | ((t2&255)<<16) | ((t3&255)<<24);
      }
    }
    // layer-0 attn gamma, bit-identical to the gq path
    float gw = anw[lane];
    float gc = gw < -2.0f ? -2.0f : (gw > 2.0f ? 2.0f : gw);
    int g = clampi((int)__builtin_rintf(gc * 1024.0f), -32768, 32767);
    #pragma unroll
    for (int pass = 0; pass < 2; pass++) {
      int t = blk*8 + pass*4 + w;       // token 0..4095
      int tok = tokens[t];
      int s = t & (T_CTX - 1);
      int tq = clampi((int)__builtin_rintf(tok_emb[tok*DM + lane] * 1024.0f), -32768, 32767);
      int pq = clampi((int)__builtin_rintf(pos_emb[s*DM + lane] * 1024.0f), -32768, 32767);
      int xv = wrap8((tq + pq) >> 3);
      x[t*DM + lane] = (int8_t)xv;
      int h = rmsnorm_one(xv, g);
      sh_h[w][lane] = (int8_t)h;                  // wave-private row: no barrier needed
      const int* h4 = (const int*)sh_h[w];
      int b = t >> 10;
      int hh = lane >> 5, d = lane & 31;
      int bhh = b*NH + hh;
      {
        int acc = 0;
        #pragma unroll
        for (int i = 0; i < 16; i++) acc = sdot4(h4[i], wqr[i], acc);
        qA[(bhh*T_CTX + s)*HD + d] = (int8_t)clampi(acc >> 6, -128, 127);
      }
      {
        int acc = 0;
        #pragma unroll
        for (int i = 0; i < 16; i++) acc = sdot4(h4[i], wkr[i], acc);
        kA[(bhh*T_CTX + s)*HD + d] = (int8_t)clampi(acc >> 6, -128, 127);
      }
      {
        int acc = 0;
        #pragma unroll
        for (int i = 0; i < 16; i++) acc = sdot4(h4[i], wvr[i], acc);
        vT[(bhh*HD + d)*T_CTX + s] = (int8_t)clampi(acc >> 6, -128, 127);
      }
    }
  }
}

// ---------------- fused layer: 512 threads = 8 tokens, wave = token (BOTH heads sequentially) ----------------
// V^T (both heads) XOR-swizzled in LDS as before. One block = (batch b, 8-token group).
// Wave w owns token s0+w: QK^T+softmax+PV for head 0 then head 1 (sc[] registers reused),
// attn output lands in wave-private sh_a32[w] -> NO cross-wave handoff. Token phase uses all 8 waves.
// Exactly ONE block barrier (V^T staging); all other LDS traffic is same-wave (per-wave DS ordering).
__global__ __launch_bounds__(512, 4) void layer_kernel(
    const int8_t* __restrict__ qA, const int8_t* __restrict__ kA, const int8_t* __restrict__ vT,
    int8_t* __restrict__ x, int8_t* __restrict__ qN, int8_t* __restrict__ kN, int8_t* __restrict__ vN,
    const int8_t* __restrict__ wt, const int16_t* __restrict__ gq, int8_t* __restrict__ xf,
    int L, int pre_layer, int do_final)
{
  __shared__ int vt32[64*256];      // 64 KB: V^T both heads, swizzled
  __shared__ int sp32[8][256];      // 8 KB: prob row per wave (reused across the 2 heads)
  __shared__ int sh_a32[8][16];     // attn output per token (wave-private)
  __shared__ int8_t sh8[8][256];    // FFN temporaries (wave-private rows)

  int tid = threadIdx.x;
  int w = tid >> 6, lane = tid & 63;
  int blk = blockIdx.x;
  int b = blk & 3;
  int s0 = 1016 - 8*(blk >> 2);     // heavy (long causal) rows dispatch first; covers s=0..1023
  int qi = s0 + w;                  // this wave's token row

  // ---- stage V^T for both heads: wave w stages rows rr = w*8 .. w*8+7 ----
  #pragma unroll
  for (int r = 0; r < 8; r++) {
    int rr = w*8 + r;
    int slot = rr >> 5, d = rr & 31;
    const int* src = (const int*)(vT + (b*NH + slot)*(HD*T_CTX) + d*T_CTX);
    int xw = ((d >> 2) & 3) << 3;
    int li = lane ^ xw;
    int* dstrow = vt32 + rr*256;
    int v0 = src[lane], v1 = src[lane+64], v2 = src[lane+128], v3 = src[lane+192];
    dstrow[li] = v0; dstrow[li+64] = v1; dstrow[li+128] = v2; dstrow[li+192] = v3;
  }

  int dg = lane & 7, kc = lane >> 3;
  int xw2 = (dg & 3) << 3;
  const int* spw = sp32[w];
  uint8_t* spb = (uint8_t*)sp32[w];

  for (int h = 0; h < 2; h++) {
    int bh = b*NH + h;
    const int8_t* qBase = qA + bh*(T_CTX*HD);
    const int8_t* kBase = kA + bh*(T_CTX*HD);

    // ---- QK^T row + hw softmax (exact) ----
    const int4* qr = (const int4*)(qBase + qi*HD);
    int4 qa = qr[0], qb = qr[1];
    int sc[16];
    int mloc = -(1 << 30);
    #pragma unroll
    for (int j = 0; j < 16; j++) {
      int k = lane + j*64;
      int s;
      if (k <= qi) {
        const int4* kr = (const int4*)(kBase + k*HD);
        int4 ka = kr[0], kb = kr[1];
        int d = 0;
        d = sdot4(qa.x, ka.x, d); d = sdot4(qa.y, ka.y, d);
        d = sdot4(qa.z, ka.z, d); d = sdot4(qa.w, ka.w, d);
        d = sdot4(qb.x, kb.x, d); d = sdot4(qb.y, kb.y, d);
        d = sdot4(qb.z, kb.z, d); d = sdot4(qb.w, kb.w, d);
        s = (d * 45) >> 8;                // floor; diag k==q gives s>=0 so the -32767 mask never wins
      } else s = -(1 << 30);
      sc[j] = s; if (s > mloc) mloc = s;
    }
    int m = wave_reduce_max(mloc);
    int ssum = 0;
    #pragma unroll
    for (int j = 0; j < 16; j++) {
      int k = lane + j*64;
      int e = 0;
      if (k <= qi) {
        int sh = sc[j] - m;               // <= 0
        e = (sh >= -3) ? (256 + sh*64)
          : (sh >= -8) ? (64 + (sh + 3)*11)
          : (sh >= -24) ? (sh + 24) : 0;
      }
      sc[j] = e; ssum += e;
    }
    int s0sum = wave_reduce_add(ssum); if (s0sum < 1) s0sum = 1;
    float sf = (float)s0sum;
    #pragma unroll
    for (int j = 0; j < 16; j++) {
      int k = lane + j*64;
      // e==0 for k>qi so the same formula writes the zero padding
      int p = (int)__builtin_rintf((float)sc[j] / sf * 255.0f);
      spb[k] = (uint8_t)clampi(p, 0, 255);
    }
    if (h == 0) __syncthreads();   // the ONE barrier: all waves' vt32 rows committed (uniform: h is uniform)

    // ---- PV via packed sdot4 from swizzled LDS: p = 2*(p>>1) + (p&1) ----
    const int* vr0 = vt32 + (h*32 + dg*4 + 0)*256;
    const int* vr1 = vt32 + (h*32 + dg*4 + 1)*256;
    const int* vr2 = vt32 + (h*32 + dg*4 + 2)*256;
    const int* vr3 = vt32 + (h*32 + dg*4 + 3)*256;
    int hi0=0, hi1=0, hi2=0, hi3=0, lo0=0, lo1=0, lo2=0, lo3=0;
    int cmax = qi >> 2;
    for (int c = kc; c <= cmax; c += 8) {
      int p4 = spw[c];                   // 8 lanes same word -> LDS broadcast
      int cs = c ^ xw2;
      int ph = (p4 >> 1) & 0x7f7f7f7f;
      int pl = p4 & 0x01010101;
      int v0 = vr0[cs], v1 = vr1[cs], v2 = vr2[cs], v3 = vr3[cs];
      hi0 = sdot4(ph, v0, hi0); lo0 = sdot4(pl, v0, lo0);
      hi1 = sdot4(ph, v1, hi1); lo1 = sdot4(pl, v1, lo1);
      hi2 = sdot4(ph, v2, hi2); lo2 = sdot4(pl, v2, lo2);
      hi3 = sdot4(ph, v3, hi3); lo3 = sdot4(pl, v3, lo3);
    }
    int a0 = 2*hi0 + lo0, a1 = 2*hi1 + lo1, a2 = 2*hi2 + lo2, a3 = 2*hi3 + lo3;
    #pragma unroll
    for (int off = 8; off < 64; off <<= 1) {
      a0 += __shfl_xor(a0, off, 64);
      a1 += __shfl_xor(a1, off, 64);
      a2 += __shfl_xor(a2, off, 64);
      a3 += __shfl_xor(a3, off, 64);
    }
    if (kc == 0) {
      int r0 = wrap8(a0 >> 8) & 255;
      int r1 = wrap8(a1 >> 8) & 255;
      int r2 = wrap8(a2 >> 8) & 255;
      int r3 = wrap8(a3 >> 8) & 255;
      int packed = r0 | (r1 << 8) | (r2 << 16) | (r3 << 24);
      sh_a32[w][h*8 + dg] = packed;      // wave-private: channel word (h*HD + dg*4)/4
    }
  }

  // ---- token phase: all 8 waves, wave w owns token s0+w; all LDS use is wave-private ----
  {
    int t = b*T_CTX + s0 + w;
    const int8_t* wtL = wt + L*49152;
    int xv = (int)x[t*DM + lane];
    { // o-projection, out channel = lane
      const int* a4 = sh_a32[w];
      const int* wo = (const int*)(wtL + 12288);
      int acc = 0;
      #pragma unroll
      for (int i = 0; i < 16; i++) acc = sdot4(a4[i], wo[lane*16 + i], acc);
      xv = wrap8(xv + clampi(acc >> 6, -128, 127));
    }
    int h2 = rmsnorm_one(xv, (int)gq[(4 + L)*DM + lane]);
    int8_t* myS = sh8[w];
    myS[lane] = (int8_t)h2;
    const int* h4 = (const int*)myS;
    int uv[4];
    { // up projection: 256 outputs, 4 per lane
      const int* wu = (const int*)(wtL + 16384);
      #pragma unroll
      for (int jj = 0; jj < 4; jj++) {
        int j = jj*64 + lane;
        int acc = 0;
        #pragma unroll
        for (int i = 0; i < 16; i++) acc = sdot4(h4[i], wu[j*16 + i], acc);
        int u = clampi(acc >> 6, -128, 127);
        uv[jj] = u < 0 ? 0 : u;           // relu (then int8 clamp is identity)
      }
    }
    #pragma unroll
    for (int jj = 0; jj < 4; jj++) myS[jj*64 + lane] = (int8_t)uv[jj];
    { // down projection: in-dim 256
      const int* u4 = (const int*)myS;
      const int* wd = (const int*)(wtL + 32768);
      int acc = 0;
      #pragma unroll
      for (int i = 0; i < 64; i++) acc = sdot4(u4[i], wd[lane*64 + i], acc);
      xv = wrap8(xv + clampi(acc >> 6, -128, 127));
    }
    x[t*DM + lane] = (int8_t)xv;
    if (pre_layer >= 0) {
      int hp = rmsnorm_one(xv, (int)gq[pre_layer*DM + lane]);
      myS[lane] = (int8_t)hp;
      const int* hp4 = (const int*)myS;
      const int8_t* wtP = wt + pre_layer*49152;
      int s = s0 + w;
      int hh = lane >> 5, d = lane & 31;
      int bhh = b*NH + hh;
      { // q
        const int* wm = (const int*)(wtP + 0);
        int acc = 0;
        #pragma unroll
        for (int i = 0; i < 16; i++) acc = sdot4(hp4[i], wm[lane*16 + i], acc);
        qN[(bhh*T_CTX + s)*HD + d] = (int8_t)clampi(acc >> 6, -128, 127);
      }
      { // k
        const int* wm = (const int*)(wtP + 4096);
        int acc = 0;
        #pragma unroll
        for (int i = 0; i < 16; i++) acc = sdot4(hp4[i], wm[lane*16 + i], acc);
        kN[(bhh*T_CTX + s)*HD + d] = (int8_t)clampi(acc >> 6, -128, 127);
      }
      { // v -> transposed layout
        const int* wm = (const int*)(wtP + 8192);
        int acc = 0;
        #pragma unroll
        for (int i = 0; i < 16; i++) acc = sdot4(hp4[i], wm[lane*16 + i], acc);
        vN[(bhh*HD + d)*T_CTX + s] = (int8_t)clampi(acc >> 6, -128, 127);
      }
    }
    if (do_final) {
      int hf = rmsnorm_one(xv, (int)gq[8*DM + lane]);
      xf[t*DM + lane] = (int8_t)hf;
    }
  }
}

// ---------------- logits: swapped-operand i8 MFMA -> D[vocab][token], float4 stores ----------------
__global__ __launch_bounds__(256) void logits_kernel(
    const int8_t* __restrict__ xf, const int8_t* __restrict__ elo, const int8_t* __restrict__ ehi,
    float* __restrict__ out)
{
  int w = threadIdx.x >> 6, lane = threadIdx.x & 63;
  int m = lane & 15, quad = lane >> 4;
  int tokBase = blockIdx.y * 64 + w * 16;
  v4i Bx = *(const v4i*)(xf + (tokBase + m)*DM + quad*16);   // B[k=quad*16+j][n=m(token)]
  float* orow = out + (tokBase + m)*NVOCAB;
  #pragma unroll
  for (int tile = 0; tile < 8; tile++) {
    int vocBase = blockIdx.x * 128 + tile * 16;
    v4i Alo = *(const v4i*)(elo + (vocBase + m)*DM + quad*16);  // A[m'=vocab row][k]
    v4i Ahi = *(const v4i*)(ehi + (vocBase + m)*DM + quad*16);
    v4i zero = {0, 0, 0, 0};
    v4i dLo = __builtin_amdgcn_mfma_i32_16x16x64_i8(Alo, Bx, zero, 0, 0, 0);
    v4i dHi = __builtin_amdgcn_mfma_i32_16x16x64_i8(Ahi, Bx, zero, 0, 0, 0);
    float4 o;
    o.x = (float)(dLo[0] + (dHi[0] << 8)) * 1.220703125e-4f;  // * 2^-13 == D^-0.5/1024
    o.y = (float)(dLo[1] + (dHi[1] << 8)) * 1.220703125e-4f;
    o.z = (float)(dLo[2] + (dHi[2] << 8)) * 1.220703125e-4f;
    o.w = (float)(dLo[3] + (dHi[3] << 8)) * 1.220703125e-4f;
    *(float4*)(orow + vocBase + quad*4) = o;                  // 16 B per lane
  }
}

extern "C" void kernel_launch(void* const* d_in, const int* in_sizes, int n_in,
                              void* d_out, int out_size, void* d_ws, size_t ws_size,
                              hipStream_t stream)
{
  const int*   tokens  = (const int*)d_in[0];
  const float* tok_emb = (const float*)d_in[1];
  const float* pos_emb = (const float*)d_in[2];
  const float* attn_nw = (const float*)d_in[3];
  const float* q_w     = (const float*)d_in[4];
  const float* k_w     = (const float*)d_in[5];
  const float* v_w     = (const float*)d_in[6];
  const float* o_w     = (const float*)d_in[7];
  const float* ff_nw   = (const float*)d_in[8];
  const float* up_w    = (const float*)d_in[9];
  const float* dn_w    = (const float*)d_in[10];
  const float* fin_nw  = (const float*)d_in[11];
  float* out = (float*)d_out;
  char* ws = (char*)d_ws;

  int8_t*  x    = (int8_t*)(ws + 0);        // 4096*64 residual stream
  int8_t*  qA0  = (int8_t*)(ws + 262144);   // [b][h][t][d] buffer 0
  int8_t*  kA0  = (int8_t*)(ws + 524288);
  int8_t*  vT0  = (int8_t*)(ws + 786432);   // [b][h][d][t]
  int8_t*  qA1  = (int8_t*)(ws + 1048576);  // buffer 1
  int8_t*  kA1  = (int8_t*)(ws + 1310720);
  int8_t*  vT1  = (int8_t*)(ws + 1572864);
  int8_t*  wt   = (int8_t*)(ws + 1835008);  // 4 layers * 49152 ternary weights
  int8_t*  elo  = (int8_t*)(ws + 2031616);  // 8192*64
  int8_t*  ehi  = (int8_t*)(ws + 2555904);  // 8192*64
  int16_t* gq   = (int16_t*)(ws + 3080192); // 9*64
  int8_t*  xf   = (int8_t*)(ws + 3081344);  // 4096*64

  prep_embed<<<1049, 256, 0, stream>>>(tokens, tok_emb, pos_emb,
                                       q_w, k_w, v_w, o_w, up_w, dn_w, attn_nw, ff_nw, fin_nw,
                                       wt, gq, elo, ehi, x, qA0, kA0, vT0);
  for (int L = 0; L < 4; L++) {
    int8_t* qC = (L & 1) ? qA1 : qA0;  int8_t* qX = (L & 1) ? qA0 : qA1;
    int8_t* kC = (L & 1) ? kA1 : kA0;  int8_t* kX = (L & 1) ? kA0 : kA1;
    int8_t* vC = (L & 1) ? vT1 : vT0;  int8_t* vX = (L & 1) ? vT0 : vT1;
    int pre = (L < 3) ? (L + 1) : -1;
    int fin = (L == 3) ? 1 : 0;
    layer_kernel<<<512, 512, 0, stream>>>(qC, kC, vC, x, qX, kX, vX, wt, gq, xf, L, pre, fin);
  }
  logits_kernel<<<dim3(64, 64), 256, 0, stream>>>(xf, elo, ehi, out);
}